// Round 2
// baseline (6320.242 us; speedup 1.0000x reference)
//
#include <hip/hip_runtime.h>
#include <math.h>

// ---------------- problem constants ----------------
// B=4096, L=64, H=64, V=21, NH=4, HD=16, FF=128, NL=2
constexpr int BATCH = 4096;

// ---------------- LDS layout (floats) ----------------
// Rotation swizzle: row-major stride 64/128, column rotated by row to avoid
// bank conflicts on the lane=row access pattern.
#define IX(base, r, c)  ((base) + ((r) << 6) + ((((c) + (r)) & 63)))
#define IXF(r, c)       (B1O + ((r) << 7) + ((((c) + (r)) & 127)))
#define IXP(r, c)       (PO + ((r) << 6) + ((((c) + (r)) & 63)))

constexpr int XO   = 0;        // x hidden state, 64x64
constexpr int B1O  = 4096;     // q / grp-q / F lower half
constexpr int B2O  = 8192;     // h (LN'd x) -> kT / grp-k / F upper half
constexpr int PO   = 12288;    // attention score/prob chunk, 32x64
constexpr int VHO  = 14336;    // per-head V slice, 64x17
constexpr int M_MASK = 15424;
constexpr int M_DVAL = M_MASK + 64;
constexpr int M_ISD  = M_MASK + 128;
constexpr int M_SU   = M_MASK + 192;  // s_up -> la -> final scores
constexpr int M_SD   = M_MASK + 256;  // s_dn -> final rw
constexpr int M_NBU  = M_MASK + 320;  // nb_up -> pooled
constexpr int M_NBD  = M_MASK + 384;
constexpr int M_DG   = M_MASK + 448;  // nb_diag -> final scalars
constexpr int M_DVEC = M_MASK + 512;
constexpr int M_S    = M_MASK + 576;  // prefix sums S[0..64] (68 slots)
constexpr int M_PRU  = M_MASK + 644;  // prior g[i,i+1]
constexpr int M_PRD  = M_MASK + 708;  // prior g[i,i]
constexpr int M_MU   = M_MASK + 772;
constexpr int M_INV  = M_MASK + 836;
constexpr int LDSN   = M_MASK + 900;  // 16324 floats = 65296 B  (<= 64KB)

// ---------------- output layout (floats) ----------------
constexpr int O_RES   = 0;
constexpr int O_REMB  = 4096;
constexpr int O_VALID = 266240;
constexpr int O_LEFT  = 270336;
constexpr int O_RIGHT = 274432;
constexpr int O_OPL   = 278528;
constexpr int O_RW    = 294912;

__device__ __forceinline__ void ln_stats(float* lds, int tid)
{
    if (tid < 64) {
        float s = 0.f, sq = 0.f;
        #pragma unroll 8
        for (int c = 0; c < 64; ++c) {
            float v = lds[IX(XO, tid, c)];
            s += v; sq = fmaf(v, v, sq);
        }
        float mu = s * (1.0f / 64.0f);
        float var = sq * (1.0f / 64.0f) - mu * mu;
        lds[M_MU + tid] = mu;
        lds[M_INV + tid] = rsqrtf(var + 1e-6f);
    }
    __syncthreads();
}

// h = LN(x)*g+b  ->  B2O buffer (row=lane layout). 256 threads, 16 cols each.
__device__ __forceinline__ void ln_to_lds(float* lds, int tid,
                                          const float* __restrict__ g,
                                          const float* __restrict__ b)
{
    const int lane = tid & 63, c0 = (tid >> 6) << 4;
    float mu = lds[M_MU + lane], inv = lds[M_INV + lane];
    #pragma unroll
    for (int j = 0; j < 16; ++j) {
        int c = c0 + j;
        lds[IX(B2O, lane, c)] = (lds[IX(XO, lane, c)] - mu) * inv * g[c] + b[c];
    }
    __syncthreads();
}

// acc[j] = bias[cb+j] + sum_kk h[lane][kk] * W[kk*ldw + cb + j]
// h read from B2O; weight rows are lane-uniform -> scalar loads.
template <int NJ, int LDW>
__device__ __forceinline__ void gemm_acc(const float* lds, int lane,
                                         const float* __restrict__ W,
                                         const float* __restrict__ bias,
                                         int cb, float* acc)
{
    #pragma unroll
    for (int j = 0; j < NJ; ++j) acc[j] = bias[cb + j];
    #pragma unroll 8
    for (int kk = 0; kk < 64; ++kk) {
        float a = lds[IX(B2O, lane, kk)];
        const float* wr = W + kk * LDW + cb;
        #pragma unroll
        for (int j = 0; j < NJ; ++j) acc[j] = fmaf(a, wr[j], acc[j]);
    }
}

__global__ void __launch_bounds__(256, 2) fsa_kernel(
    const int* __restrict__ tok,
    const float* __restrict__ emb, const float* __restrict__ np_w, const float* __restrict__ np_b,
    const float* __restrict__ grp_wq, const float* __restrict__ grp_bq,
    const float* __restrict__ grp_wk, const float* __restrict__ grp_bk,
    const float* __restrict__ grp_ln_g, const float* __restrict__ grp_ln_b,
    const float* __restrict__ attn_w, const float* __restrict__ attn_b,
    const float* __restrict__ ln1_g, const float* __restrict__ ln1_b,
    const float* __restrict__ ln2_g, const float* __restrict__ ln2_b,
    const float* __restrict__ ffn_w1, const float* __restrict__ ffn_b1,
    const float* __restrict__ ffn_w2, const float* __restrict__ ffn_b2,
    const float* __restrict__ enc_g, const float* __restrict__ enc_b,
    const float* __restrict__ red_w, const float* __restrict__ red_b,
    const float* __restrict__ opc_w, const float* __restrict__ opc_b,
    const float* __restrict__ res_w, const float* __restrict__ res_b,
    float* __restrict__ out)
{
    __shared__ float lds[LDSN];
    const int b = blockIdx.x;
    const int tid = threadIdx.x;
    const int lane = tid & 63;
    const int wv = __builtin_amdgcn_readfirstlane(tid >> 6);
    const int c0 = wv << 4;

    // ================= embedding + positional encoding =================
    {
        int t = tok[(b << 6) + lane];
        float mk  = (t != 0) ? 1.f : 0.f;
        float isd = (t >= 4 && t <= 13) ? 1.f : 0.f;
        float dvv = ((float)t - 4.f) * isd;
        float iso = (t >= 14 && t <= 17) ? 1.f : 0.f;
        float opt = iso * ((float)t - 13.f);
        if (wv == 0) {
            lds[M_MASK + lane] = mk;  lds[M_DVAL + lane] = dvv; lds[M_ISD + lane] = isd;
            lds[M_PRU + lane] = 0.f;  lds[M_PRD + lane] = 0.f;
        }
        const float lg = -0.143911568f;   // -ln(10000)/64
        #pragma unroll
        for (int j = 0; j < 16; ++j) {
            int c = c0 + j;
            float freq = expf((float)(c & ~1) * lg);
            float ang = (float)lane * freq;
            float pe = (c & 1) ? cosf(ang) : sinf(ang);
            float val = emb[t * 64 + c] * 8.f
                      + dvv * np_w[c] + isd * np_w[64 + c]
                      + opt * np_w[128 + c] + iso * np_w[192 + c]
                      + np_b[c] + pe;
            lds[IX(XO, lane, c)] = val;
        }
    }
    __syncthreads();

    // ================= transformer layers =================
    for (int il = 0; il < 2; ++il) {
        const float* gwq = grp_wq + il * 4096; const float* gbq = grp_bq + (il << 6);
        const float* gwk = grp_wk + il * 4096; const float* gbk = grp_bk + (il << 6);
        const float* glg = grp_ln_g + (il << 6); const float* glb = grp_ln_b + (il << 6);
        const float* aw  = attn_w + il * 16384;  const float* ab  = attn_b + (il << 8);
        const float* l1g = ln1_g + (il << 6);    const float* l1b = ln1_b + (il << 6);
        const float* l2g = ln2_g + (il << 6);    const float* l2b = ln2_b + (il << 6);
        const float* fw1 = ffn_w1 + il * 8192;   const float* fb1 = ffn_b1 + (il << 7);
        const float* fw2 = ffn_w2 + il * 8192;   const float* fb2 = ffn_b2 + (il << 6);

        // ---- group (constituent) attention: only adjacent links matter ----
        ln_stats(lds, tid);
        ln_to_lds(lds, tid, glg, glb);          // h -> B2O
        {
            float qa[16];
            gemm_acc<16, 64>(lds, lane, gwq, gbq, c0, qa);
            #pragma unroll
            for (int j = 0; j < 16; ++j) lds[IX(B1O, lane, c0 + j)] = qa[j];
            float ka[16];
            gemm_acc<16, 64>(lds, lane, gwk, gbk, c0, ka);
            __syncthreads();                    // h reads + B1O writes complete
            #pragma unroll
            for (int j = 0; j < 16; ++j) lds[IX(B2O, lane, c0 + j)] = ka[j];
            __syncthreads();
        }

        if (tid < 126) {              // s[i,i+1] and s[i+1,i]
            int i = tid >> 1, w = tid & 1;
            int ra = w ? i + 1 : i, rb = w ? i : i + 1;
            float s = 0.f;
            #pragma unroll 8
            for (int c2 = 0; c2 < 64; ++c2)
                s = fmaf(lds[IX(B1O, ra, c2)], lds[IX(B2O, rb, c2)], s);
            lds[(w ? M_SD : M_SU) + i] = s * 0.125f;   // / sqrt(H)
        }
        __syncthreads();

        if (tid < 64) {               // masked row softmax (<=2 finite entries)
            int i = tid;
            float mi = lds[M_MASK + i];
            float eu = (i < 63 && mi > 0.f && lds[M_MASK + i + 1] > 0.f) ? lds[M_SU + i] : -1e9f;
            float ed = (i > 0  && mi > 0.f && lds[M_MASK + i - 1] > 0.f) ? lds[M_SD + i - 1] : -1e9f;
            float m = fmaxf(eu, ed);
            float nu, nd, ng;
            if (m <= -1e9f) { nu = 0.015625f; nd = 0.015625f; ng = 0.015625f; }  // uniform 1/64
            else {
                float zu = expf(eu - m), zd = expf(ed - m);
                float iz = 1.f / (zu + zd);
                nu = zu * iz; nd = zd * iz; ng = 0.f;
            }
            lds[M_NBU + i] = nu; lds[M_NBD + i] = nd; lds[M_DG + i] = ng;
        }
        __syncthreads();

        if (tid < 64) {               // symmetrize + prior mix + log
            int i = tid;
            float pd = lds[M_PRD + i];
            float dg = lds[M_DG + i];
            float dsym = sqrtf(dg * dg + 1e-9f);
            float d2 = pd + (1.f - pd) * dsym;
            lds[M_DVEC + i] = d2;
            lds[M_PRD + i] = d2;
            if (i < 63) {
                float pu = lds[M_PRU + i];
                float as = sqrtf(lds[M_NBU + i] * lds[M_NBD + i + 1] + 1e-9f);
                float a2 = pu + (1.f - pu) * as;
                float la = logf(a2 + 1e-9f);
                lds[M_SU + i] = la;                  // reuse as la[]
                lds[M_PRU + i] = expf(la) + 1e-9f;   // next-layer prior g[i,i+1]
            }
        }
        __syncthreads();
        if (tid == 0) {               // prefix sums of la
            float s = 0.f; lds[M_S] = 0.f;
            for (int i2 = 0; i2 < 63; ++i2) { s += lds[M_SU + i2]; lds[M_S + i2 + 1] = s; }
        }
        __syncthreads();

        // ---- multi-head attention, weighted by g ----
        ln_stats(lds, tid);
        ln_to_lds(lds, tid, l1g, l1b);          // h -> B2O
        float va[16];                            // V[lane][c0..c0+15] carried in regs
        {
            float qa[16];
            gemm_acc<16, 64>(lds, lane, aw, ab, c0, qa);               // Q
            #pragma unroll
            for (int j = 0; j < 16; ++j) lds[IX(B1O, lane, c0 + j)] = qa[j];
            gemm_acc<16, 64>(lds, lane, aw + 8192, ab + 128, c0, va);  // V (regs)
            float ka[16];
            gemm_acc<16, 64>(lds, lane, aw + 4096, ab + 64, c0, ka);   // K
            __syncthreads();                    // h reads + B1O writes complete
            #pragma unroll
            for (int j = 0; j < 16; ++j) lds[IX(B2O, c0 + j, lane)] = ka[j];  // K^T
            __syncthreads();
        }
        const float* Wo = aw + 12288; const float* bo = ab + 192;
        const int rl = tid >> 3, jg = tid & 7;

        for (int hh = 0; hh < 4; ++hh) {
            if (wv == hh) {                      // this wave owns head hh's V cols
                #pragma unroll
                for (int j = 0; j < 16; ++j) lds[VHO + lane * 17 + j] = va[j];
            }
            __syncthreads();
            for (int rh = 0; rh < 2; ++rh) {
                const int r = (rh << 5) + rl;
                const int hb = hh << 4;
                // scores + softmax + g
                {
                    float sc[8];
                    #pragma unroll
                    for (int j = 0; j < 8; ++j) sc[j] = 0.f;
                    #pragma unroll
                    for (int d = 0; d < 16; ++d) {
                        float a = lds[IX(B1O, r, hb + d)];
                        #pragma unroll
                        for (int j = 0; j < 8; ++j)
                            sc[j] = fmaf(a, lds[IX(B2O, hb + d, (jg << 3) + j)], sc[j]);
                    }
                    float m = -1e9f;
                    #pragma unroll
                    for (int j = 0; j < 8; ++j) {
                        int jj = (jg << 3) + j;
                        sc[j] = (lds[M_MASK + jj] > 0.f) ? sc[j] * 0.25f : -1e9f;
                        m = fmaxf(m, sc[j]);
                    }
                    m = fmaxf(m, __shfl_xor(m, 1));
                    m = fmaxf(m, __shfl_xor(m, 2));
                    m = fmaxf(m, __shfl_xor(m, 4));
                    float e[8];
                    float z = 0.f;
                    #pragma unroll
                    for (int j = 0; j < 8; ++j) { e[j] = expf(sc[j] - m); z += e[j]; }
                    z += __shfl_xor(z, 1); z += __shfl_xor(z, 2); z += __shfl_xor(z, 4);
                    float iz = 1.f / z;
                    float Sr = lds[M_S + r];
                    #pragma unroll
                    for (int j = 0; j < 8; ++j) {
                        int jj = (jg << 3) + j;
                        float gij;
                        if (jj == r) gij = lds[M_DVEC + r];
                        else {
                            float Sj = lds[M_S + jj];
                            gij = expf((jj > r) ? (Sj - Sr) : (Sr - Sj)) + 1e-9f;
                        }
                        e[j] = e[j] * iz * gij;
                    }
                    #pragma unroll
                    for (int j = 0; j < 8; ++j) lds[IXP(rl, (jg << 3) + j)] = e[j];
                }
                __syncthreads();
                // P @ V_head
                const int dd0 = jg << 1;
                float o0 = 0.f, o1 = 0.f;
                #pragma unroll 8
                for (int j = 0; j < 64; ++j) {
                    float pj = lds[IXP(rl, j)];
                    o0 = fmaf(pj, lds[VHO + j * 17 + dd0], o0);
                    o1 = fmaf(pj, lds[VHO + j * 17 + dd0 + 1], o1);
                }
                __syncthreads();
                lds[IXP(rl, dd0)] = o0;
                lds[IXP(rl, dd0 + 1)] = o1;
                __syncthreads();
                // output projection, accumulate into x (bias added once at hh==0)
                {
                    const int cc = jg << 3;
                    float acc2[8];
                    #pragma unroll
                    for (int j = 0; j < 8; ++j) acc2[j] = (hh == 0) ? bo[cc + j] : 0.f;
                    #pragma unroll
                    for (int dd = 0; dd < 16; ++dd) {
                        float ov = lds[IXP(rl, dd)];
                        const float* wr = Wo + (hb + dd) * 64 + cc;
                        #pragma unroll
                        for (int j = 0; j < 8; ++j) acc2[j] = fmaf(ov, wr[j], acc2[j]);
                    }
                    #pragma unroll
                    for (int j = 0; j < 8; ++j) lds[IX(XO, r, cc + j)] += acc2[j];
                }
                __syncthreads();
            }
        }

        // ---- FFN ----
        ln_stats(lds, tid);
        ln_to_lds(lds, tid, l2g, l2b);          // h -> B2O
        {   // f = relu(h @ W1 + b1), 64x128, stored over B1+B2 (after barrier)
            const int cf = wv << 5;
            float fa[32];
            gemm_acc<32, 128>(lds, lane, fw1, fb1, cf, fa);
            __syncthreads();                    // all h reads complete
            #pragma unroll
            for (int j = 0; j < 32; ++j) lds[IXF(lane, cf + j)] = fmaxf(fa[j], 0.f);
            __syncthreads();
        }
        {   // x += f @ W2 + b2
            float acc[16];
            #pragma unroll
            for (int j = 0; j < 16; ++j) acc[j] = fb2[c0 + j];
            #pragma unroll 8
            for (int kk = 0; kk < 128; ++kk) {
                float a = lds[IXF(lane, kk)];
                const float* wr = fw2 + kk * 64 + c0;
                #pragma unroll
                for (int j = 0; j < 16; ++j) acc[j] = fmaf(a, wr[j], acc[j]);
            }
            #pragma unroll
            for (int j = 0; j < 16; ++j) lds[IX(XO, lane, c0 + j)] += acc[j];
            __syncthreads();
        }
    }

    // ================= reduction / calculator head =================
    ln_stats(lds, tid);   // enc LN stats
    if (tid < 64) {       // scores = h @ red_w + red_b + (1-mask)*-1e9
        float mu = lds[M_MU + tid], inv = lds[M_INV + tid];
        float s = 0.f;
        #pragma unroll 8
        for (int c2 = 0; c2 < 64; ++c2) {
            float hv = (lds[IX(XO, tid, c2)] - mu) * inv * enc_g[c2] + enc_b[c2];
            s = fmaf(hv, red_w[c2], s);
        }
        s += red_b[0];
        s += (1.f - lds[M_MASK + tid]) * -1e9f;
        lds[M_SU + tid] = s;
    }
    __syncthreads();

    if (wv == 0) {        // softmax, scans, digit assembly (wave 0)
        float s = lds[M_SU + lane];
        float m = s;
        #pragma unroll
        for (int off = 1; off < 64; off <<= 1) m = fmaxf(m, __shfl_xor(m, off));
        float ee = expf(s - m);
        float z = ee;
        #pragma unroll
        for (int off = 1; off < 64; off <<= 1) z += __shfl_xor(z, off);
        float rw = ee / z;
        lds[M_SD + lane] = rw;
        float cum = rw;
        #pragma unroll
        for (int off = 1; off < 64; off <<= 1) { float t2 = __shfl_up(cum, off); if (lane >= off) cum += t2; }
        float isd = lds[M_ISD + lane], dvv = lds[M_DVAL + lane];
        float lm = (1.f - cum) * isd;
        float rm = (cum - rw) * isd;
        // left value
        float cl = lm;
        #pragma unroll
        for (int off = 1; off < 64; off <<= 1) { float t2 = __shfl_up(cl, off); if (lane >= off) cl += t2; }
        float totl = __shfl(cl, 63);
        float wL = powf(10.f, (totl - cl) * lm) * lm;
        float lv = dvv * wL;
        #pragma unroll
        for (int off = 1; off < 64; off <<= 1) lv += __shfl_xor(lv, off);
        // right value
        float cr = rm;
        #pragma unroll
        for (int off = 1; off < 64; off <<= 1) { float t2 = __shfl_up(cr, off); if (lane >= off) cr += t2; }
        float totr = __shfl(cr, 63);
        float wR = powf(10.f, (totr - cr) * rm) * rm;
        float rv = dvv * wR;
        #pragma unroll
        for (int off = 1; off < 64; off <<= 1) rv += __shfl_xor(rv, off);
        if (lane == 0) { lds[M_DG + 2] = lv; lds[M_DG + 3] = rv; }
    }
    __syncthreads();

    if (tid < 64) {       // pooled = sum_r h[r,:] * rw[r]
        float eg = enc_g[tid], eb = enc_b[tid];
        float p = 0.f;
        #pragma unroll 8
        for (int r2 = 0; r2 < 64; ++r2) {
            float hv = (lds[IX(XO, r2, tid)] - lds[M_MU + r2]) * lds[M_INV + r2] * eg + eb;
            p = fmaf(hv, lds[M_SD + r2], p);
        }
        lds[M_NBU + tid] = p;
    }
    __syncthreads();
    if (tid < 4) {        // op logits
        float s = opc_b[tid];
        for (int c2 = 0; c2 < 64; ++c2) s = fmaf(lds[M_NBU + c2], opc_w[(c2 << 2) + tid], s);
        lds[M_DG + 4 + tid] = s;
    }
    __syncthreads();
    if (tid == 0) {       // hard argmax op select + fixed ops
        float l = lds[M_DG + 2], r = lds[M_DG + 3];
        float o0 = lds[M_DG + 4], o1 = lds[M_DG + 5], o2 = lds[M_DG + 6], o3 = lds[M_DG + 7];
        int op = 0; float bm = o0;
        if (o1 > bm) { bm = o1; op = 1; }
        if (o2 > bm) { bm = o2; op = 2; }
        if (o3 > bm) { bm = o3; op = 3; }
        float res, vl = 1.f;
        if (op == 0)      res = l + r;
        else if (op == 1) res = l - r;
        else if (op == 2) res = l * r;
        else { bool bad = fabsf(r) < 1e-6f; res = bad ? 0.f : (l / r); vl = bad ? 0.f : 1.f; }
        float rc = (res > 0.f) ? log1pf(res) : ((res < 0.f) ? -log1pf(-res) : 0.f);
        lds[M_DG + 0] = rc; lds[M_DG + 1] = vl;
        out[O_RES + b]   = res;
        out[O_VALID + b] = vl;
        out[O_LEFT + b]  = l;
        out[O_RIGHT + b] = r;
    }
    __syncthreads();
    if (tid < 64) {
        float rc = lds[M_DG + 0], vl = lds[M_DG + 1];
        out[O_REMB + (b << 6) + tid] = rc * res_w[tid] + vl * res_w[64 + tid] + res_b[tid];
        out[O_RW + (b << 6) + tid] = lds[M_SD + tid];
    }
    if (tid >= 64 && tid < 68) {
        int o = tid - 64;
        out[O_OPL + (b << 2) + o] = lds[M_DG + 4 + o];
    }
}

extern "C" void kernel_launch(void* const* d_in, const int* in_sizes, int n_in,
                              void* d_out, int out_size, void* d_ws, size_t ws_size,
                              hipStream_t stream)
{
    fsa_kernel<<<dim3(BATCH), dim3(256), 0, stream>>>(
        (const int*)d_in[0],
        (const float*)d_in[1],  (const float*)d_in[2],  (const float*)d_in[3],
        (const float*)d_in[4],  (const float*)d_in[5],  (const float*)d_in[6],  (const float*)d_in[7],
        (const float*)d_in[8],  (const float*)d_in[9],  (const float*)d_in[10], (const float*)d_in[11],
        (const float*)d_in[12], (const float*)d_in[13], (const float*)d_in[14], (const float*)d_in[15],
        (const float*)d_in[16], (const float*)d_in[17], (const float*)d_in[18], (const float*)d_in[19],
        (const float*)d_in[20], (const float*)d_in[21], (const float*)d_in[22], (const float*)d_in[23],
        (const float*)d_in[24], (const float*)d_in[25], (const float*)d_in[26], (const float*)d_in[27],
        (float*)d_out);
}

// Round 3
// 2203.240 us; speedup vs baseline: 2.8686x; 2.8686x over previous
//
#include <hip/hip_runtime.h>
#include <math.h>

// B=4096, L=64, H=64, V=21, NH=4, HD=16, FF=128, NL=2
constexpr int BATCH = 4096;

// Rotation swizzle: bank = ((c + r) & 63) % 32 varies with r for fixed c
// (column reads conflict-free) and with c for fixed r (row reads 2-way = free).
#define IX(base, r, c)  ((base) + ((r) << 6) + ((((c) + (r)) & 63)))
#define IXP(r, c)       (PO + ((r) << 6) + ((((c) + (r)) & 63)))

constexpr int VO   = 0;        // grp-K / V / F-hi  (64x64)
constexpr int B1O  = 4096;     // grp-Q / Q -> PV out / F-lo
constexpr int B2O  = 8192;     // h (LN'd x) -> K row-major
constexpr int PO   = 12288;    // attention prob chunk, 32x64
constexpr int PS   = 14336;    // LN partial sums, 4x64
constexpr int PSQ  = 14592;    // LN partial sumsq, 4x64
constexpr int M_MASK = 14848;
constexpr int M_DVAL = M_MASK + 64;
constexpr int M_ISD  = M_MASK + 128;
constexpr int M_SU   = M_MASK + 192;  // s_up -> la -> final scores
constexpr int M_SD   = M_MASK + 256;  // s_dn -> final rw
constexpr int M_NBU  = M_MASK + 320;  // nb_up -> pooled
constexpr int M_NBD  = M_MASK + 384;
constexpr int M_DG   = M_MASK + 448;  // nb_diag -> final scalars
constexpr int M_DVEC = M_MASK + 512;
constexpr int M_S    = M_MASK + 576;  // prefix sums S[0..64]
constexpr int M_PRU  = M_MASK + 644;  // prior g[i,i+1]
constexpr int M_PRD  = M_MASK + 708;  // prior g[i,i]
constexpr int LDSN   = M_MASK + 772;  // 15620 floats = 62480 B

// ---------------- output layout (floats) ----------------
constexpr int O_RES   = 0;
constexpr int O_REMB  = 4096;
constexpr int O_VALID = 266240;
constexpr int O_LEFT  = 270336;
constexpr int O_RIGHT = 274432;
constexpr int O_OPL   = 278528;
constexpr int O_RW    = 294912;

// LN of xr -> h in B2O. 2 barriers. All locals scoped, constant-indexed.
#define LN_H(GPTR, BPTR) do {                                                 \
    float s_ = 0.f, q_ = 0.f;                                                 \
    _Pragma("unroll") for (int j = 0; j < 16; ++j) {                          \
        s_ += xr[j]; q_ = fmaf(xr[j], xr[j], q_); }                           \
    lds[PS  + (wv << 6) + lane] = s_;                                         \
    lds[PSQ + (wv << 6) + lane] = q_;                                         \
    __syncthreads();                                                          \
    float fs_ = lds[PS + lane] + lds[PS + 64 + lane]                          \
              + lds[PS + 128 + lane] + lds[PS + 192 + lane];                  \
    float fq_ = lds[PSQ + lane] + lds[PSQ + 64 + lane]                        \
              + lds[PSQ + 128 + lane] + lds[PSQ + 192 + lane];                \
    float mu_ = fs_ * (1.f / 64.f);                                           \
    float inv_ = rsqrtf(fq_ * (1.f / 64.f) - mu_ * mu_ + 1e-6f);              \
    _Pragma("unroll") for (int j = 0; j < 16; ++j) {                          \
        int c_ = c0 + j;                                                      \
        lds[IX(B2O, lane, c_)] = (xr[j] - mu_) * inv_ * (GPTR)[c_] + (BPTR)[c_]; } \
    __syncthreads();                                                          \
} while (0)

// acc_[16] = bias[c0+j] + sum_kk lds[IX(SRC,lane,kk)] * W[kk*64 + c0 + j]
// Manual 8x outer unroll; every array index is a compile-time constant.
#define GEMM16(SRC, W, BIAS, STORE) do {                                      \
    float acc_[16];                                                           \
    _Pragma("unroll") for (int j = 0; j < 16; ++j) acc_[j] = (BIAS)[c0 + j];  \
    for (int kb = 0; kb < 64; kb += 8) {                                      \
        _Pragma("unroll") for (int ku = 0; ku < 8; ++ku) {                    \
            int kk_ = kb + ku;                                                \
            float a_ = lds[IX(SRC, lane, kk_)];                               \
            const float* wr_ = (W) + kk_ * 64 + c0;                           \
            _Pragma("unroll") for (int j = 0; j < 16; ++j)                    \
                acc_[j] = fmaf(a_, wr_[j], acc_[j]); } }                      \
    _Pragma("unroll") for (int j = 0; j < 16; ++j) { STORE; }                 \
} while (0)

__global__ void __launch_bounds__(256, 2) fsa_kernel(
    const int* __restrict__ tok,
    const float* __restrict__ emb, const float* __restrict__ np_w, const float* __restrict__ np_b,
    const float* __restrict__ grp_wq, const float* __restrict__ grp_bq,
    const float* __restrict__ grp_wk, const float* __restrict__ grp_bk,
    const float* __restrict__ grp_ln_g, const float* __restrict__ grp_ln_b,
    const float* __restrict__ attn_w, const float* __restrict__ attn_b,
    const float* __restrict__ ln1_g, const float* __restrict__ ln1_b,
    const float* __restrict__ ln2_g, const float* __restrict__ ln2_b,
    const float* __restrict__ ffn_w1, const float* __restrict__ ffn_b1,
    const float* __restrict__ ffn_w2, const float* __restrict__ ffn_b2,
    const float* __restrict__ enc_g, const float* __restrict__ enc_b,
    const float* __restrict__ red_w, const float* __restrict__ red_b,
    const float* __restrict__ opc_w, const float* __restrict__ opc_b,
    const float* __restrict__ res_w, const float* __restrict__ res_b,
    float* __restrict__ out)
{
    __shared__ float lds[LDSN];
    const int b = blockIdx.x;
    const int tid = threadIdx.x;
    const int lane = tid & 63;
    const int wv = __builtin_amdgcn_readfirstlane(tid >> 6);
    const int c0 = wv << 4;
    float xr[16];   // x[lane][c0 .. c0+15] lives in registers

    // ================= embedding + positional encoding =================
    {
        int t = tok[(b << 6) + lane];
        float mk  = (t != 0) ? 1.f : 0.f;
        float isd = (t >= 4 && t <= 13) ? 1.f : 0.f;
        float dvv = ((float)t - 4.f) * isd;
        float iso = (t >= 14 && t <= 17) ? 1.f : 0.f;
        float opt = iso * ((float)t - 13.f);
        if (wv == 0) {
            lds[M_MASK + lane] = mk;  lds[M_DVAL + lane] = dvv; lds[M_ISD + lane] = isd;
            lds[M_PRU + lane] = 0.f;  lds[M_PRD + lane] = 0.f;
        }
        const float lg = -0.143911568f;   // -ln(10000)/64
        #pragma unroll
        for (int j = 0; j < 16; ++j) {
            int c = c0 + j;
            float freq = expf((float)(c & ~1) * lg);
            float ang = (float)lane * freq;
            float pe = (c & 1) ? cosf(ang) : sinf(ang);
            xr[j] = emb[t * 64 + c] * 8.f
                  + dvv * np_w[c] + isd * np_w[64 + c]
                  + opt * np_w[128 + c] + iso * np_w[192 + c]
                  + np_b[c] + pe;
        }
    }
    // (visibility of M_MASK etc. covered by LN_H's barrier)

    // ================= transformer layers =================
    for (int il = 0; il < 2; ++il) {
        const float* gwq = grp_wq + il * 4096; const float* gbq = grp_bq + (il << 6);
        const float* gwk = grp_wk + il * 4096; const float* gbk = grp_bk + (il << 6);
        const float* glg = grp_ln_g + (il << 6); const float* glb = grp_ln_b + (il << 6);
        const float* aw  = attn_w + il * 16384;  const float* ab  = attn_b + (il << 8);
        const float* l1g = ln1_g + (il << 6);    const float* l1b = ln1_b + (il << 6);
        const float* l2g = ln2_g + (il << 6);    const float* l2b = ln2_b + (il << 6);
        const float* fw1 = ffn_w1 + il * 8192;   const float* fb1 = ffn_b1 + (il << 7);
        const float* fw2 = ffn_w2 + il * 8192;   const float* fb2 = ffn_b2 + (il << 6);

        // ---- group (constituent) attention: only adjacent links matter ----
        LN_H(glg, glb);
        GEMM16(B2O, gwq, gbq, lds[IX(B1O, lane, c0 + j)] = acc_[j]);   // grp Q
        GEMM16(B2O, gwk, gbk, lds[IX(VO,  lane, c0 + j)] = acc_[j]);   // grp K
        __syncthreads();

        if (tid < 126) {              // s[i,i+1] and s[i+1,i]
            int i = tid >> 1, w = tid & 1;
            int ra = w ? i + 1 : i, rb = w ? i : i + 1;
            float s = 0.f;
            #pragma unroll 8
            for (int c2 = 0; c2 < 64; ++c2)
                s = fmaf(lds[IX(B1O, ra, c2)], lds[IX(VO, rb, c2)], s);
            lds[(w ? M_SD : M_SU) + i] = s * 0.125f;   // / sqrt(H)
        }
        __syncthreads();

        if (tid < 64) {               // masked row softmax (<=2 finite entries)
            int i = tid;
            float mi = lds[M_MASK + i];
            float eu = (i < 63 && mi > 0.f && lds[M_MASK + i + 1] > 0.f) ? lds[M_SU + i] : -1e9f;
            float ed = (i > 0  && mi > 0.f && lds[M_MASK + i - 1] > 0.f) ? lds[M_SD + i - 1] : -1e9f;
            float m = fmaxf(eu, ed);
            float nu, nd, ng;
            if (m <= -1e9f) { nu = 0.015625f; nd = 0.015625f; ng = 0.015625f; }  // uniform 1/64
            else {
                float zu = expf(eu - m), zd = expf(ed - m);
                float iz = 1.f / (zu + zd);
                nu = zu * iz; nd = zd * iz; ng = 0.f;
            }
            lds[M_NBU + i] = nu; lds[M_NBD + i] = nd; lds[M_DG + i] = ng;
        }
        __syncthreads();

        if (tid < 64) {               // symmetrize + prior mix + log
            int i = tid;
            float pd = lds[M_PRD + i];
            float dg = lds[M_DG + i];
            float dsym = sqrtf(dg * dg + 1e-9f);
            float d2 = pd + (1.f - pd) * dsym;
            lds[M_DVEC + i] = d2;
            lds[M_PRD + i] = d2;
            if (i < 63) {
                float pu = lds[M_PRU + i];
                float as = sqrtf(lds[M_NBU + i] * lds[M_NBD + i + 1] + 1e-9f);
                float a2 = pu + (1.f - pu) * as;
                float la = logf(a2 + 1e-9f);
                lds[M_SU + i] = la;                  // reuse as la[]
                lds[M_PRU + i] = expf(la) + 1e-9f;   // next-layer prior g[i,i+1]
            }
        }
        __syncthreads();
        if (tid == 0) {               // prefix sums of la
            float s = 0.f; lds[M_S] = 0.f;
            for (int i2 = 0; i2 < 63; ++i2) { s += lds[M_SU + i2]; lds[M_S + i2 + 1] = s; }
        }
        __syncthreads();

        // ---- multi-head attention, weighted by g ----
        LN_H(l1g, l1b);
        GEMM16(B2O, aw,        ab,        lds[IX(B1O, lane, c0 + j)] = acc_[j]);  // Q
        GEMM16(B2O, aw + 8192, ab + 128,  lds[IX(VO,  lane, c0 + j)] = acc_[j]);  // V row-major
        float ka[16];
        GEMM16(B2O, aw + 4096, ab + 64,   ka[j] = acc_[j]);                       // K -> regs
        __syncthreads();              // all h reads done; Q,V visible
        #pragma unroll
        for (int j = 0; j < 16; ++j) lds[IX(B2O, lane, c0 + j)] = ka[j];          // K row-major
        __syncthreads();

        const int rl = tid >> 3, jg = tid & 7;
        const int pr = tid & 31, cg = tid >> 5;

        for (int hh = 0; hh < 4; ++hh) {
            const int hb = hh << 4;
            for (int rh = 0; rh < 2; ++rh) {
                // ---- scores + softmax + g -> PO ----
                {
                    const int r = (rh << 5) + rl;
                    float sc[8];
                    #pragma unroll
                    for (int j = 0; j < 8; ++j) sc[j] = 0.f;
                    #pragma unroll
                    for (int d = 0; d < 16; ++d) {
                        float a = lds[IX(B1O, r, hb + d)];
                        #pragma unroll
                        for (int j = 0; j < 8; ++j)
                            sc[j] = fmaf(a, lds[IX(B2O, (jg << 3) + j, hb + d)], sc[j]);
                    }
                    float m = -1e9f;
                    #pragma unroll
                    for (int j = 0; j < 8; ++j) {
                        int jj = (jg << 3) + j;
                        sc[j] = (lds[M_MASK + jj] > 0.f) ? sc[j] * 0.25f : -1e9f;
                        m = fmaxf(m, sc[j]);
                    }
                    m = fmaxf(m, __shfl_xor(m, 1));
                    m = fmaxf(m, __shfl_xor(m, 2));
                    m = fmaxf(m, __shfl_xor(m, 4));
                    float e[8];
                    float z = 0.f;
                    #pragma unroll
                    for (int j = 0; j < 8; ++j) { e[j] = expf(sc[j] - m); z += e[j]; }
                    z += __shfl_xor(z, 1); z += __shfl_xor(z, 2); z += __shfl_xor(z, 4);
                    float iz = 1.f / z;
                    float Sr = lds[M_S + r];
                    #pragma unroll
                    for (int j = 0; j < 8; ++j) {
                        int jj = (jg << 3) + j;
                        float gij;
                        if (jj == r) gij = lds[M_DVEC + r];
                        else {
                            float Sj = lds[M_S + jj];
                            gij = expf((jj > r) ? (Sj - Sr) : (Sr - Sj)) + 1e-9f;
                        }
                        lds[IXP(rl, jj)] = e[j] * iz * gij;
                    }
                }
                __syncthreads();
                // ---- P @ V_head -> overwrite Q's dead cols in B1O ----
                {
                    const int row2 = (rh << 5) + pr;
                    const int cc = hb + (cg << 1);
                    float o0 = 0.f, o1 = 0.f;
                    #pragma unroll 8
                    for (int j = 0; j < 64; ++j) {
                        float pj = lds[IXP(pr, j)];
                        o0 = fmaf(pj, lds[IX(VO, j, cc)], o0);
                        o1 = fmaf(pj, lds[IX(VO, j, cc + 1)], o1);
                    }
                    lds[IX(B1O, row2, cc)]     = o0;
                    lds[IX(B1O, row2, cc + 1)] = o1;
                }
                __syncthreads();
            }
        }
        // ---- output projection: xr += concat(PV) @ Wo + bo ----
        {
            const float* Wo = aw + 12288; const float* bo = ab + 192;
            float acc_[16];
            #pragma unroll
            for (int j = 0; j < 16; ++j) acc_[j] = bo[c0 + j];
            for (int kb = 0; kb < 64; kb += 8) {
                #pragma unroll
                for (int ku = 0; ku < 8; ++ku) {
                    int dd = kb + ku;
                    float a = lds[IX(B1O, lane, dd)];
                    const float* wr_ = Wo + dd * 64 + c0;
                    #pragma unroll
                    for (int j = 0; j < 16; ++j) acc_[j] = fmaf(a, wr_[j], acc_[j]);
                }
            }
            #pragma unroll
            for (int j = 0; j < 16; ++j) xr[j] += acc_[j];
        }
        // (B1O/VO reads complete before LN_H barrier -> safe to overwrite after)

        // ---- FFN ----
        LN_H(l2g, l2b);
        {   // F = relu(h @ W1 + b1): cols 0..63 -> B1O, cols 64..127 -> VO
            const int cf = wv << 5;
            float fa[32];
            #pragma unroll
            for (int j = 0; j < 32; ++j) fa[j] = fb1[cf + j];
            for (int kb = 0; kb < 64; kb += 8) {
                #pragma unroll
                for (int ku = 0; ku < 8; ++ku) {
                    int kk = kb + ku;
                    float a = lds[IX(B2O, lane, kk)];
                    const float* wr_ = fw1 + kk * 128 + cf;
                    #pragma unroll
                    for (int j = 0; j < 32; ++j) fa[j] = fmaf(a, wr_[j], fa[j]);
                }
            }
            if (wv < 2) {
                #pragma unroll
                for (int j = 0; j < 32; ++j) lds[IX(B1O, lane, cf + j)] = fmaxf(fa[j], 0.f);
            } else {
                #pragma unroll
                for (int j = 0; j < 32; ++j) lds[IX(VO, lane, cf - 64 + j)] = fmaxf(fa[j], 0.f);
            }
            __syncthreads();
        }
        {   // xr += F @ W2 + b2
            float acc_[16];
            #pragma unroll
            for (int j = 0; j < 16; ++j) acc_[j] = fb2[c0 + j];
            for (int kb = 0; kb < 64; kb += 8) {
                #pragma unroll
                for (int ku = 0; ku < 8; ++ku) {
                    int kk = kb + ku;
                    float a = lds[IX(B1O, lane, kk)];
                    const float* wr_ = fw2 + kk * 64 + c0;
                    #pragma unroll
                    for (int j = 0; j < 16; ++j) acc_[j] = fmaf(a, wr_[j], acc_[j]);
                }
            }
            for (int kb = 0; kb < 64; kb += 8) {
                #pragma unroll
                for (int ku = 0; ku < 8; ++ku) {
                    int kk = kb + ku;
                    float a = lds[IX(VO, lane, kk)];
                    const float* wr_ = fw2 + (64 + kk) * 64 + c0;
                    #pragma unroll
                    for (int j = 0; j < 16; ++j) acc_[j] = fmaf(a, wr_[j], acc_[j]);
                }
            }
            #pragma unroll
            for (int j = 0; j < 16; ++j) xr[j] += acc_[j];
        }
        __syncthreads();   // F reads done before next layer overwrites B1O/VO/B2O
    }

    // ================= reduction / calculator head =================
    LN_H(enc_g, enc_b);   // final h -> B2O
    if (tid < 64) {       // scores = h @ red_w + red_b + (1-mask)*-1e9
        float s = 0.f;
        #pragma unroll 8
        for (int c2 = 0; c2 < 64; ++c2)
            s = fmaf(lds[IX(B2O, tid, c2)], red_w[c2], s);
        s += red_b[0];
        s += (1.f - lds[M_MASK + tid]) * -1e9f;
        lds[M_SU + tid] = s;
    }
    __syncthreads();

    if (wv == 0) {        // softmax, scans, digit assembly (wave 0)
        float s = lds[M_SU + lane];
        float m = s;
        #pragma unroll
        for (int off = 1; off < 64; off <<= 1) m = fmaxf(m, __shfl_xor(m, off));
        float ee = expf(s - m);
        float z = ee;
        #pragma unroll
        for (int off = 1; off < 64; off <<= 1) z += __shfl_xor(z, off);
        float rw = ee / z;
        lds[M_SD + lane] = rw;
        float cum = rw;
        #pragma unroll
        for (int off = 1; off < 64; off <<= 1) { float t2 = __shfl_up(cum, off); if (lane >= off) cum += t2; }
        float isd = lds[M_ISD + lane], dvv = lds[M_DVAL + lane];
        float lm = (1.f - cum) * isd;
        float rm = (cum - rw) * isd;
        float cl = lm;
        #pragma unroll
        for (int off = 1; off < 64; off <<= 1) { float t2 = __shfl_up(cl, off); if (lane >= off) cl += t2; }
        float totl = __shfl(cl, 63);
        float wL = powf(10.f, (totl - cl) * lm) * lm;
        float lv = dvv * wL;
        #pragma unroll
        for (int off = 1; off < 64; off <<= 1) lv += __shfl_xor(lv, off);
        float cr = rm;
        #pragma unroll
        for (int off = 1; off < 64; off <<= 1) { float t2 = __shfl_up(cr, off); if (lane >= off) cr += t2; }
        float totr = __shfl(cr, 63);
        float wR = powf(10.f, (totr - cr) * rm) * rm;
        float rv = dvv * wR;
        #pragma unroll
        for (int off = 1; off < 64; off <<= 1) rv += __shfl_xor(rv, off);
        if (lane == 0) { lds[M_DG + 2] = lv; lds[M_DG + 3] = rv; }
    }
    __syncthreads();

    if (tid < 64) {       // pooled = sum_r h[r,:] * rw[r]
        float p = 0.f;
        #pragma unroll 8
        for (int r2 = 0; r2 < 64; ++r2)
            p = fmaf(lds[IX(B2O, r2, tid)], lds[M_SD + r2], p);
        lds[M_NBU + tid] = p;
    }
    __syncthreads();
    if (tid < 4) {        // op logits
        float s = opc_b[tid];
        for (int c2 = 0; c2 < 64; ++c2) s = fmaf(lds[M_NBU + c2], opc_w[(c2 << 2) + tid], s);
        lds[M_DG + 4 + tid] = s;
    }
    __syncthreads();
    if (tid == 0) {       // hard argmax op select + fixed ops
        float l = lds[M_DG + 2], r = lds[M_DG + 3];
        float o0 = lds[M_DG + 4], o1 = lds[M_DG + 5], o2 = lds[M_DG + 6], o3 = lds[M_DG + 7];
        int op = 0; float bm = o0;
        if (o1 > bm) { bm = o1; op = 1; }
        if (o2 > bm) { bm = o2; op = 2; }
        if (o3 > bm) { bm = o3; op = 3; }
        float res, vl = 1.f;
        if (op == 0)      res = l + r;
        else if (op == 1) res = l - r;
        else if (op == 2) res = l * r;
        else { bool bad = fabsf(r) < 1e-6f; res = bad ? 0.f : (l / r); vl = bad ? 0.f : 1.f; }
        float rc = (res > 0.f) ? log1pf(res) : ((res < 0.f) ? -log1pf(-res) : 0.f);
        lds[M_DG + 0] = rc; lds[M_DG + 1] = vl;
        out[O_RES + b]   = res;
        out[O_VALID + b] = vl;
        out[O_LEFT + b]  = l;
        out[O_RIGHT + b] = r;
    }
    __syncthreads();
    if (tid < 64) {
        float rc = lds[M_DG + 0], vl = lds[M_DG + 1];
        out[O_REMB + (b << 6) + tid] = rc * res_w[tid] + vl * res_w[64 + tid] + res_b[tid];
        out[O_RW + (b << 6) + tid] = lds[M_SD + tid];
    }
    if (tid >= 64 && tid < 68) {
        int o = tid - 64;
        out[O_OPL + (b << 2) + o] = lds[M_DG + 4 + o];
    }
}

extern "C" void kernel_launch(void* const* d_in, const int* in_sizes, int n_in,
                              void* d_out, int out_size, void* d_ws, size_t ws_size,
                              hipStream_t stream)
{
    fsa_kernel<<<dim3(BATCH), dim3(256), 0, stream>>>(
        (const int*)d_in[0],
        (const float*)d_in[1],  (const float*)d_in[2],  (const float*)d_in[3],
        (const float*)d_in[4],  (const float*)d_in[5],  (const float*)d_in[6],  (const float*)d_in[7],
        (const float*)d_in[8],  (const float*)d_in[9],  (const float*)d_in[10], (const float*)d_in[11],
        (const float*)d_in[12], (const float*)d_in[13], (const float*)d_in[14], (const float*)d_in[15],
        (const float*)d_in[16], (const float*)d_in[17], (const float*)d_in[18], (const float*)d_in[19],
        (const float*)d_in[20], (const float*)d_in[21], (const float*)d_in[22], (const float*)d_in[23],
        (const float*)d_in[24], (const float*)d_in[25], (const float*)d_in[26], (const float*)d_in[27],
        (float*)d_out);
}

// Round 4
// 1895.563 us; speedup vs baseline: 3.3342x; 1.1623x over previous
//
#include <hip/hip_runtime.h>
#include <math.h>

// B=4096, L=64, H=64, V=21, NH=4, HD=16, FF=128, NL=2
constexpr int BATCH = 4096;

// ---------------- LDS regions (float indices) ----------------
// VR  [0,4352): V row-major stride 68 (16B-aligned rows, conflict-free b128)
//               also grp-KT (stride 64) / FFN F-hi (stride 64) / final hR (stride 65)
// QTB [4352,8448): transposed [c][r] stride 64: grp-QT / Q / OT / F-lo; PS/PSQ during LN
// HTB [8448,12800): hT [c][r] stride 64, then K row-major stride 68
// M   [12800,13568)
constexpr int VR   = 0;
constexpr int QTB  = 4352;
constexpr int HTB  = 8448;
constexpr int PS   = QTB;          // 4x64, only live inside LN
constexpr int PSQ  = QTB + 256;
constexpr int MB     = 12800;
constexpr int M_MASK = MB;
constexpr int M_DVAL = MB + 64;
constexpr int M_ISD  = MB + 128;
constexpr int M_SU   = MB + 192;   // s_up -> la -> final scores
constexpr int M_SD   = MB + 256;   // s_dn -> final rw
constexpr int M_NBU  = MB + 320;   // nb_up -> pooled
constexpr int M_NBD  = MB + 384;
constexpr int M_DG   = MB + 448;   // nb_diag -> final scalars
constexpr int M_DVEC = MB + 512;
constexpr int M_S    = MB + 576;   // prefix sums S[0..63]
constexpr int M_PRU  = MB + 640;   // prior g[i,i+1]
constexpr int M_PRD  = MB + 704;   // prior g[i,i]
constexpr int LDSN   = MB + 768;   // 13568 floats = 54272 B -> 3 blocks/CU

// ---------------- output layout (floats) ----------------
constexpr int O_RES   = 0;
constexpr int O_REMB  = 4096;
constexpr int O_VALID = 266240;
constexpr int O_LEFT  = 270336;
constexpr int O_RIGHT = 274432;
constexpr int O_OPL   = 278528;
constexpr int O_RW    = 294912;

// LN of xr; stats via 4-wave LDS partial reduce; then STORE h per column.
#define LN_STORE(GPTR, BPTR, STORE) do {                                  \
    float s_ = 0.f, q_ = 0.f;                                             \
    _Pragma("unroll") for (int j = 0; j < 16; ++j) {                      \
        s_ += xr[j]; q_ = fmaf(xr[j], xr[j], q_); }                       \
    lds[PS  + (wv << 6) + lane] = s_;                                     \
    lds[PSQ + (wv << 6) + lane] = q_;                                     \
    __syncthreads();                                                      \
    float fs_ = lds[PS + lane] + lds[PS + 64 + lane]                      \
              + lds[PS + 128 + lane] + lds[PS + 192 + lane];              \
    float fq_ = lds[PSQ + lane] + lds[PSQ + 64 + lane]                    \
              + lds[PSQ + 128 + lane] + lds[PSQ + 192 + lane];            \
    float mu_ = fs_ * 0.015625f;                                          \
    float inv_ = rsqrtf(fq_ * 0.015625f - mu_ * mu_ + 1e-6f);             \
    _Pragma("unroll") for (int j = 0; j < 16; ++j) {                      \
        int c_ = c0 + j;                                                  \
        float hv_ = (xr[j] - mu_) * inv_ * (GPTR)[c_] + (BPTR)[c_];       \
        STORE;                                                            \
    }                                                                     \
    __syncthreads();                                                      \
} while (0)

__global__ void __launch_bounds__(256, 3) fsa_kernel(
    const int* __restrict__ tok,
    const float* __restrict__ emb, const float* __restrict__ np_w, const float* __restrict__ np_b,
    const float* __restrict__ grp_wq, const float* __restrict__ grp_bq,
    const float* __restrict__ grp_wk, const float* __restrict__ grp_bk,
    const float* __restrict__ grp_ln_g, const float* __restrict__ grp_ln_b,
    const float* __restrict__ attn_w, const float* __restrict__ attn_b,
    const float* __restrict__ ln1_g, const float* __restrict__ ln1_b,
    const float* __restrict__ ln2_g, const float* __restrict__ ln2_b,
    const float* __restrict__ ffn_w1, const float* __restrict__ ffn_b1,
    const float* __restrict__ ffn_w2, const float* __restrict__ ffn_b2,
    const float* __restrict__ enc_g, const float* __restrict__ enc_b,
    const float* __restrict__ red_w, const float* __restrict__ red_b,
    const float* __restrict__ opc_w, const float* __restrict__ opc_b,
    const float* __restrict__ res_w, const float* __restrict__ res_b,
    float* __restrict__ out)
{
    __shared__ __align__(16) float lds[LDSN];
    const int b = blockIdx.x;
    const int tid = threadIdx.x;
    const int lane = tid & 63;
    const int wv = __builtin_amdgcn_readfirstlane(tid >> 6);
    const int c0 = wv << 4;
    const int rl = tid >> 3;      // 0..31 (attention row, +32 for second row)
    const int jg = tid & 7;       // score-col group: j = ju*8 + jg
    float xr[16];                 // x[lane][c0 .. c0+15] in registers

    // ================= embedding + positional encoding =================
    {
        int t = tok[(b << 6) + lane];
        float mk  = (t != 0) ? 1.f : 0.f;
        float isd = (t >= 4 && t <= 13) ? 1.f : 0.f;
        float dvv = ((float)t - 4.f) * isd;
        float iso = (t >= 14 && t <= 17) ? 1.f : 0.f;
        float opt = iso * ((float)t - 13.f);
        if (wv == 0) {
            lds[M_MASK + lane] = mk;  lds[M_DVAL + lane] = dvv; lds[M_ISD + lane] = isd;
            lds[M_PRU + lane] = 0.f;  lds[M_PRD + lane] = 0.f;
        }
        const float lg = -0.143911568f;   // -ln(10000)/64
        #pragma unroll
        for (int j = 0; j < 16; ++j) {
            int c = c0 + j;
            float freq = expf((float)(c & ~1) * lg);
            float ang = (float)lane * freq;
            float pe = (c & 1) ? cosf(ang) : sinf(ang);
            xr[j] = emb[t * 64 + c] * 8.f
                  + dvv * np_w[c] + isd * np_w[64 + c]
                  + opt * np_w[128 + c] + iso * np_w[192 + c]
                  + np_b[c] + pe;
        }
    }

    // ================= transformer layers =================
    for (int il = 0; il < 2; ++il) {
        const float* gwq = grp_wq + il * 4096; const float* gbq = grp_bq + (il << 6);
        const float* gwk = grp_wk + il * 4096; const float* gbk = grp_bk + (il << 6);
        const float* glg = grp_ln_g + (il << 6); const float* glb = grp_ln_b + (il << 6);
        const float* aw  = attn_w + il * 16384;  const float* ab  = attn_b + (il << 8);
        const float* l1g = ln1_g + (il << 6);    const float* l1b = ln1_b + (il << 6);
        const float* l2g = ln2_g + (il << 6);    const float* l2b = ln2_b + (il << 6);
        const float* fw1 = ffn_w1 + il * 8192;   const float* fb1 = ffn_b1 + (il << 7);
        const float* fw2 = ffn_w2 + il * 8192;   const float* fb2 = ffn_b2 + (il << 6);

        // ---- group (constituent) attention ----
        LN_STORE(glg, glb, lds[HTB + c_ * 64 + lane] = hv_);
        {   // fused gq/gk GEMM streaming hT
            float qa[16], ka[16];
            #pragma unroll
            for (int j = 0; j < 16; ++j) { qa[j] = gbq[c0 + j]; ka[j] = gbk[c0 + j]; }
            #pragma unroll 8
            for (int kk = 0; kk < 64; ++kk) {
                float a = lds[HTB + kk * 64 + lane];
                const float* wq = gwq + kk * 64 + c0;
                const float* wk = gwk + kk * 64 + c0;
                #pragma unroll
                for (int j = 0; j < 16; ++j) {
                    qa[j] = fmaf(a, wq[j], qa[j]);
                    ka[j] = fmaf(a, wk[j], ka[j]);
                }
            }
            // gQT -> QTB, gKT -> VR (neither overlaps hT; PS reads done at LN barrier)
            #pragma unroll
            for (int j = 0; j < 16; ++j) {
                lds[QTB + (c0 + j) * 64 + lane] = qa[j];
                lds[VR  + (c0 + j) * 64 + lane] = ka[j];
            }
        }
        __syncthreads();

        if (tid < 126) {              // s[i,i+1] and s[i+1,i]
            int i = tid >> 1, w = tid & 1;
            int ra = w ? i + 1 : i, rb = w ? i : i + 1;
            float s = 0.f;
            #pragma unroll 8
            for (int c2 = 0; c2 < 64; ++c2)
                s = fmaf(lds[QTB + c2 * 64 + ra], lds[VR + c2 * 64 + rb], s);
            lds[(w ? M_SD : M_SU) + i] = s * 0.125f;   // / sqrt(H)
        }
        __syncthreads();

        if (tid < 64) {               // masked row softmax (<=2 finite entries)
            int i = tid;
            float mi = lds[M_MASK + i];
            float eu = (i < 63 && mi > 0.f && lds[M_MASK + i + 1] > 0.f) ? lds[M_SU + i] : -1e9f;
            float ed = (i > 0  && mi > 0.f && lds[M_MASK + i - 1] > 0.f) ? lds[M_SD + i - 1] : -1e9f;
            float m = fmaxf(eu, ed);
            float nu, nd, ng;
            if (m <= -1e9f) { nu = 0.015625f; nd = 0.015625f; ng = 0.015625f; }
            else {
                float zu = expf(eu - m), zd = expf(ed - m);
                float iz = 1.f / (zu + zd);
                nu = zu * iz; nd = zd * iz; ng = 0.f;
            }
            lds[M_NBU + i] = nu; lds[M_NBD + i] = nd; lds[M_DG + i] = ng;
        }
        __syncthreads();

        if (tid < 64) {               // symmetrize + prior mix + log
            int i = tid;
            float pd = lds[M_PRD + i];
            float dg = lds[M_DG + i];
            float dsym = sqrtf(dg * dg + 1e-9f);
            float d2 = pd + (1.f - pd) * dsym;
            lds[M_DVEC + i] = d2;
            lds[M_PRD + i] = d2;
            if (i < 63) {
                float pu = lds[M_PRU + i];
                float as = sqrtf(lds[M_NBU + i] * lds[M_NBD + i + 1] + 1e-9f);
                float a2 = pu + (1.f - pu) * as;
                float la = logf(a2 + 1e-9f);
                lds[M_SU + i] = la;                  // reuse as la[]
                lds[M_PRU + i] = expf(la) + 1e-9f;   // next-layer prior g[i,i+1]
            }
        }
        __syncthreads();
        if (tid == 0) {               // prefix sums of la
            float s = 0.f; lds[M_S] = 0.f;
            for (int i2 = 0; i2 < 63; ++i2) { s += lds[M_SU + i2]; lds[M_S + i2 + 1] = s; }
        }
        __syncthreads();

        // ---- multi-head attention, weighted by g ----
        LN_STORE(l1g, l1b, lds[HTB + c_ * 64 + lane] = hv_);
        {   // fused Q/K/V GEMM streaming hT
            float qa[16], ka[16], va[16];
            #pragma unroll
            for (int j = 0; j < 16; ++j) {
                qa[j] = ab[c0 + j]; ka[j] = ab[64 + c0 + j]; va[j] = ab[128 + c0 + j];
            }
            #pragma unroll 8
            for (int kk = 0; kk < 64; ++kk) {
                float a = lds[HTB + kk * 64 + lane];
                const float* wq = aw + kk * 64 + c0;
                const float* wk = aw + 4096 + kk * 64 + c0;
                const float* wvp = aw + 8192 + kk * 64 + c0;
                #pragma unroll
                for (int j = 0; j < 16; ++j) {
                    qa[j] = fmaf(a, wq[j], qa[j]);
                    ka[j] = fmaf(a, wk[j], ka[j]);
                    va[j] = fmaf(a, wvp[j], va[j]);
                }
            }
            __syncthreads();          // all hT reads done before K overwrites HTB
            #pragma unroll
            for (int j = 0; j < 16; ++j) {
                lds[QTB + (c0 + j) * 64 + lane] = qa[j];   // Q transposed [c][r]
                lds[HTB + lane * 68 + c0 + j]  = ka[j];    // K row-major stride 68
                lds[VR  + lane * 68 + c0 + j]  = va[j];    // V row-major stride 68
            }
        }
        __syncthreads();

        for (int hh = 0; hh < 4; ++hh) {
            const int hb = hh << 4;
            // q for rows rl and rl+32 (transposed reads, static offsets)
            float q0[16], q1[16];
            #pragma unroll
            for (int d = 0; d < 16; ++d) {
                q0[d] = lds[QTB + (hb + d) * 64 + rl];
                q1[d] = lds[QTB + (hb + d) * 64 + rl + 32];
            }
            // scores for cols j = ju*8+jg via b128 K-row reads
            float sc0[8], sc1[8];
            #pragma unroll
            for (int ju = 0; ju < 8; ++ju) {
                float s0 = 0.f, s1 = 0.f;
                #pragma unroll
                for (int c4 = 0; c4 < 4; ++c4) {
                    const float4 kv = *reinterpret_cast<const float4*>(
                        &lds[HTB + jg * 68 + ju * 544 + hb + (c4 << 2)]);
                    s0 = fmaf(q0[(c4<<2)+0], kv.x, s0); s0 = fmaf(q0[(c4<<2)+1], kv.y, s0);
                    s0 = fmaf(q0[(c4<<2)+2], kv.z, s0); s0 = fmaf(q0[(c4<<2)+3], kv.w, s0);
                    s1 = fmaf(q1[(c4<<2)+0], kv.x, s1); s1 = fmaf(q1[(c4<<2)+1], kv.y, s1);
                    s1 = fmaf(q1[(c4<<2)+2], kv.z, s1); s1 = fmaf(q1[(c4<<2)+3], kv.w, s1);
                }
                sc0[ju] = s0; sc1[ju] = s1;
            }
            // mask + softmax (reduce over jg lanes) + g-weighting
            float m0 = -1e9f, m1 = -1e9f;
            #pragma unroll
            for (int ju = 0; ju < 8; ++ju) {
                float mk = lds[M_MASK + ju * 8 + jg];
                sc0[ju] = (mk > 0.f) ? sc0[ju] * 0.25f : -1e9f;
                sc1[ju] = (mk > 0.f) ? sc1[ju] * 0.25f : -1e9f;
                m0 = fmaxf(m0, sc0[ju]); m1 = fmaxf(m1, sc1[ju]);
            }
            m0 = fmaxf(m0, __shfl_xor(m0, 1)); m0 = fmaxf(m0, __shfl_xor(m0, 2)); m0 = fmaxf(m0, __shfl_xor(m0, 4));
            m1 = fmaxf(m1, __shfl_xor(m1, 1)); m1 = fmaxf(m1, __shfl_xor(m1, 2)); m1 = fmaxf(m1, __shfl_xor(m1, 4));
            float z0 = 0.f, z1 = 0.f;
            float p0[8], p1[8];
            #pragma unroll
            for (int ju = 0; ju < 8; ++ju) {
                p0[ju] = expf(sc0[ju] - m0); z0 += p0[ju];
                p1[ju] = expf(sc1[ju] - m1); z1 += p1[ju];
            }
            z0 += __shfl_xor(z0, 1); z0 += __shfl_xor(z0, 2); z0 += __shfl_xor(z0, 4);
            z1 += __shfl_xor(z1, 1); z1 += __shfl_xor(z1, 2); z1 += __shfl_xor(z1, 4);
            float iz0 = 1.f / z0, iz1 = 1.f / z1;
            float Sr0 = lds[M_S + rl], Sr1 = lds[M_S + rl + 32];
            float dv0 = lds[M_DVEC + rl], dv1 = lds[M_DVEC + rl + 32];
            #pragma unroll
            for (int ju = 0; ju < 8; ++ju) {
                int jj = ju * 8 + jg;
                float Sj = lds[M_S + jj];
                float g0 = (jj == rl)      ? dv0 : (expf((jj > rl)      ? (Sj - Sr0) : (Sr0 - Sj)) + 1e-9f);
                float g1 = (jj == rl + 32) ? dv1 : (expf((jj > rl + 32) ? (Sj - Sr1) : (Sr1 - Sj)) + 1e-9f);
                p0[ju] = p0[ju] * iz0 * g0;
                p1[ju] = p1[ju] * iz1 * g1;
            }
            // PV partials over own 8 j's (b128 V-row reads), then butterfly over jg
            float po0[16], po1[16];
            #pragma unroll
            for (int c = 0; c < 16; ++c) { po0[c] = 0.f; po1[c] = 0.f; }
            #pragma unroll
            for (int ju = 0; ju < 8; ++ju) {
                #pragma unroll
                for (int c4 = 0; c4 < 4; ++c4) {
                    const float4 v = *reinterpret_cast<const float4*>(
                        &lds[VR + jg * 68 + ju * 544 + hb + (c4 << 2)]);
                    po0[(c4<<2)+0] = fmaf(p0[ju], v.x, po0[(c4<<2)+0]);
                    po0[(c4<<2)+1] = fmaf(p0[ju], v.y, po0[(c4<<2)+1]);
                    po0[(c4<<2)+2] = fmaf(p0[ju], v.z, po0[(c4<<2)+2]);
                    po0[(c4<<2)+3] = fmaf(p0[ju], v.w, po0[(c4<<2)+3]);
                    po1[(c4<<2)+0] = fmaf(p1[ju], v.x, po1[(c4<<2)+0]);
                    po1[(c4<<2)+1] = fmaf(p1[ju], v.y, po1[(c4<<2)+1]);
                    po1[(c4<<2)+2] = fmaf(p1[ju], v.z, po1[(c4<<2)+2]);
                    po1[(c4<<2)+3] = fmaf(p1[ju], v.w, po1[(c4<<2)+3]);
                }
            }
            #pragma unroll
            for (int c = 0; c < 16; ++c) {
                po0[c] += __shfl_xor(po0[c], 1); po0[c] += __shfl_xor(po0[c], 2); po0[c] += __shfl_xor(po0[c], 4);
                po1[c] += __shfl_xor(po1[c], 1); po1[c] += __shfl_xor(po1[c], 2); po1[c] += __shfl_xor(po1[c], 4);
            }
            __syncthreads();          // all Q-reads of this head done before O overwrites
            if (jg == 0) {            // write O cols of this head (Q cols now dead)
                #pragma unroll
                for (int c = 0; c < 16; ++c) {
                    lds[QTB + (hb + c) * 64 + rl]      = po0[c];
                    lds[QTB + (hb + c) * 64 + rl + 32] = po1[c];
                }
            }
        }
        __syncthreads();
        // ---- output projection: xr += O @ Wo + bo ----
        {
            const float* Wo = aw + 12288; const float* bo = ab + 192;
            float acc[16];
            #pragma unroll
            for (int j = 0; j < 16; ++j) acc[j] = bo[c0 + j];
            #pragma unroll 8
            for (int dd = 0; dd < 64; ++dd) {
                float a = lds[QTB + dd * 64 + lane];
                const float* wr = Wo + dd * 64 + c0;
                #pragma unroll
                for (int j = 0; j < 16; ++j) acc[j] = fmaf(a, wr[j], acc[j]);
            }
            #pragma unroll
            for (int j = 0; j < 16; ++j) xr[j] += acc[j];
        }
        __syncthreads();              // O reads done before LN2's PS writes (PS in QTB)

        // ---- FFN ----
        LN_STORE(l2g, l2b, lds[HTB + c_ * 64 + lane] = hv_);
        {   // F = relu(h @ W1 + b1): 32 cols per wave
            const int cf = wv << 5;
            float fa[32];
            #pragma unroll
            for (int j = 0; j < 32; ++j) fa[j] = fb1[cf + j];
            #pragma unroll 8
            for (int kk = 0; kk < 64; ++kk) {
                float a = lds[HTB + kk * 64 + lane];
                const float* wr = fw1 + kk * 128 + cf;
                #pragma unroll
                for (int j = 0; j < 32; ++j) fa[j] = fmaf(a, wr[j], fa[j]);
            }
            // FT-lo -> QTB (cols 0..63), FT-hi -> VR (cols 64..127); no hT conflict
            if (wv < 2) {
                #pragma unroll
                for (int j = 0; j < 32; ++j) lds[QTB + (cf + j) * 64 + lane] = fmaxf(fa[j], 0.f);
            } else {
                #pragma unroll
                for (int j = 0; j < 32; ++j) lds[VR + (cf - 64 + j) * 64 + lane] = fmaxf(fa[j], 0.f);
            }
        }
        __syncthreads();
        {   // xr += F @ W2 + b2
            float acc[16];
            #pragma unroll
            for (int j = 0; j < 16; ++j) acc[j] = fb2[c0 + j];
            #pragma unroll 8
            for (int kk = 0; kk < 64; ++kk) {
                float a = lds[QTB + kk * 64 + lane];
                const float* wr = fw2 + kk * 64 + c0;
                #pragma unroll
                for (int j = 0; j < 16; ++j) acc[j] = fmaf(a, wr[j], acc[j]);
            }
            #pragma unroll 8
            for (int kk = 0; kk < 64; ++kk) {
                float a = lds[VR + kk * 64 + lane];
                const float* wr = fw2 + (64 + kk) * 64 + c0;
                #pragma unroll
                for (int j = 0; j < 16; ++j) acc[j] = fmaf(a, wr[j], acc[j]);
            }
            #pragma unroll
            for (int j = 0; j < 16; ++j) xr[j] += acc[j];
        }
        __syncthreads();              // F reads done before next layer reuses regions
    }

    // ================= reduction / calculator head =================
    // final LN -> hR row-major stride 65 in VR
    LN_STORE(enc_g, enc_b, lds[VR + lane * 65 + c_] = hv_);
    if (tid < 64) {       // scores = h @ red_w + red_b + (1-mask)*-1e9
        float s = 0.f;
        #pragma unroll 8
        for (int c2 = 0; c2 < 64; ++c2)
            s = fmaf(lds[VR + tid * 65 + c2], red_w[c2], s);
        s += red_b[0];
        s += (1.f - lds[M_MASK + tid]) * -1e9f;
        lds[M_SU + tid] = s;
    }
    __syncthreads();

    if (wv == 0) {        // softmax, scans, digit assembly (wave 0)
        float s = lds[M_SU + lane];
        float m = s;
        #pragma unroll
        for (int off = 1; off < 64; off <<= 1) m = fmaxf(m, __shfl_xor(m, off));
        float ee = expf(s - m);
        float z = ee;
        #pragma unroll
        for (int off = 1; off < 64; off <<= 1) z += __shfl_xor(z, off);
        float rw = ee / z;
        lds[M_SD + lane] = rw;
        float cum = rw;
        #pragma unroll
        for (int off = 1; off < 64; off <<= 1) { float t2 = __shfl_up(cum, off); if (lane >= off) cum += t2; }
        float isd = lds[M_ISD + lane], dvv = lds[M_DVAL + lane];
        float lm = (1.f - cum) * isd;
        float rm = (cum - rw) * isd;
        float cl = lm;
        #pragma unroll
        for (int off = 1; off < 64; off <<= 1) { float t2 = __shfl_up(cl, off); if (lane >= off) cl += t2; }
        float totl = __shfl(cl, 63);
        float wL = powf(10.f, (totl - cl) * lm) * lm;
        float lv = dvv * wL;
        #pragma unroll
        for (int off = 1; off < 64; off <<= 1) lv += __shfl_xor(lv, off);
        float cr = rm;
        #pragma unroll
        for (int off = 1; off < 64; off <<= 1) { float t2 = __shfl_up(cr, off); if (lane >= off) cr += t2; }
        float totr = __shfl(cr, 63);
        float wR = powf(10.f, (totr - cr) * rm) * rm;
        float rv = dvv * wR;
        #pragma unroll
        for (int off = 1; off < 64; off <<= 1) rv += __shfl_xor(rv, off);
        if (lane == 0) { lds[M_DG + 2] = lv; lds[M_DG + 3] = rv; }
    }
    __syncthreads();

    if (tid < 64) {       // pooled[c] = sum_r h[r][c] * rw[r]
        float p = 0.f;
        #pragma unroll 8
        for (int r2 = 0; r2 < 64; ++r2)
            p = fmaf(lds[VR + r2 * 65 + tid], lds[M_SD + r2], p);
        lds[M_NBU + tid] = p;
    }
    __syncthreads();
    if (tid < 4) {        // op logits
        float s = opc_b[tid];
        for (int c2 = 0; c2 < 64; ++c2) s = fmaf(lds[M_NBU + c2], opc_w[(c2 << 2) + tid], s);
        lds[M_DG + 4 + tid] = s;
    }
    __syncthreads();
    if (tid == 0) {       // hard argmax op select + fixed ops
        float l = lds[M_DG + 2], r = lds[M_DG + 3];
        float o0 = lds[M_DG + 4], o1 = lds[M_DG + 5], o2 = lds[M_DG + 6], o3 = lds[M_DG + 7];
        int op = 0; float bm = o0;
        if (o1 > bm) { bm = o1; op = 1; }
        if (o2 > bm) { bm = o2; op = 2; }
        if (o3 > bm) { bm = o3; op = 3; }
        float res, vl = 1.f;
        if (op == 0)      res = l + r;
        else if (op == 1) res = l - r;
        else if (op == 2) res = l * r;
        else { bool bad = fabsf(r) < 1e-6f; res = bad ? 0.f : (l / r); vl = bad ? 0.f : 1.f; }
        float rc = (res > 0.f) ? log1pf(res) : ((res < 0.f) ? -log1pf(-res) : 0.f);
        lds[M_DG + 0] = rc; lds[M_DG + 1] = vl;
        out[O_RES + b]   = res;
        out[O_VALID + b] = vl;
        out[O_LEFT + b]  = l;
        out[O_RIGHT + b] = r;
    }
    __syncthreads();
    if (tid < 64) {
        float rc = lds[M_DG + 0], vl = lds[M_DG + 1];
        out[O_REMB + (b << 6) + tid] = rc * res_w[tid] + vl * res_w[64 + tid] + res_b[tid];
        out[O_RW + (b << 6) + tid] = lds[M_SD + tid];
    }
    if (tid >= 64 && tid < 68) {
        int o = tid - 64;
        out[O_OPL + (b << 2) + o] = lds[M_DG + 4 + o];
    }
}

extern "C" void kernel_launch(void* const* d_in, const int* in_sizes, int n_in,
                              void* d_out, int out_size, void* d_ws, size_t ws_size,
                              hipStream_t stream)
{
    fsa_kernel<<<dim3(BATCH), dim3(256), 0, stream>>>(
        (const int*)d_in[0],
        (const float*)d_in[1],  (const float*)d_in[2],  (const float*)d_in[3],
        (const float*)d_in[4],  (const float*)d_in[5],  (const float*)d_in[6],  (const float*)d_in[7],
        (const float*)d_in[8],  (const float*)d_in[9],  (const float*)d_in[10], (const float*)d_in[11],
        (const float*)d_in[12], (const float*)d_in[13], (const float*)d_in[14], (const float*)d_in[15],
        (const float*)d_in[16], (const float*)d_in[17], (const float*)d_in[18], (const float*)d_in[19],
        (const float*)d_in[20], (const float*)d_in[21], (const float*)d_in[22], (const float*)d_in[23],
        (const float*)d_in[24], (const float*)d_in[25], (const float*)d_in[26], (const float*)d_in[27],
        (float*)d_out);
}

// Round 5
// 1848.854 us; speedup vs baseline: 3.4185x; 1.0253x over previous
//
#include <hip/hip_runtime.h>
#include <math.h>

// B=4096, L=64, H=64, V=21, NH=4, HD=16, FF=128, NL=2
constexpr int BATCH = 4096;

// ---------------- LDS regions (float indices), total 39,936 B -> 4 blocks/CU
// A  [0,4352):    hT [c][r] stride 64  /  gK^T stride 64
// Bb [4352,8704): gQ^T stride 64 / {QH,KH,VH 64x20} / F^T stride 64 / hR stride 65
// M  [8704,9984): masks, scan state, LN partials
constexpr int A    = 0;
constexpr int Bb   = 4352;
constexpr int QH   = Bb;            // 64x20
constexpr int KH   = Bb + 1280;     // 64x20
constexpr int VH   = Bb + 2560;     // 64x20
constexpr int MB   = 8704;
constexpr int M_MASK = MB + 0;
constexpr int M_DVAL = MB + 64;
constexpr int M_ISD  = MB + 128;
constexpr int M_SD   = MB + 192;    // final rw
constexpr int M_NBU  = MB + 256;    // pooled
constexpr int M_DG   = MB + 320;    // scalars
constexpr int M_DVEC = MB + 384;    // g diagonal
constexpr int M_S    = MB + 448;    // prefix sums
constexpr int M_PRU  = MB + 512;    // prior g[i,i+1]
constexpr int M_PRD  = MB + 576;    // prior g[i,i]
constexpr int M_SU   = MB + 640;    // s_up
constexpr int M_SDN  = MB + 704;    // s_dn
constexpr int PS     = MB + 768;    // 4x64 LN partial sums
constexpr int PSQ    = MB + 1024;   // 4x64 LN partial sumsq
constexpr int LDSN   = MB + 1280;   // 9984 floats = 39,936 B

// ---------------- output layout (floats) ----------------
constexpr int O_RES   = 0;
constexpr int O_REMB  = 4096;
constexpr int O_VALID = 266240;
constexpr int O_LEFT  = 270336;
constexpr int O_RIGHT = 274432;
constexpr int O_OPL   = 278528;
constexpr int O_RW    = 294912;

// LN of xr; stats via 4-wave LDS partial reduce; then STORE per column.
#define LN_STORE(GPTR, BPTR, STORE) do {                                  \
    float s_ = 0.f, q_ = 0.f;                                             \
    _Pragma("unroll") for (int j = 0; j < 16; ++j) {                      \
        s_ += xr[j]; q_ = fmaf(xr[j], xr[j], q_); }                       \
    lds[PS  + (wv << 6) + lane] = s_;                                     \
    lds[PSQ + (wv << 6) + lane] = q_;                                     \
    __syncthreads();                                                      \
    float fs_ = lds[PS + lane] + lds[PS + 64 + lane]                      \
              + lds[PS + 128 + lane] + lds[PS + 192 + lane];              \
    float fq_ = lds[PSQ + lane] + lds[PSQ + 64 + lane]                    \
              + lds[PSQ + 128 + lane] + lds[PSQ + 192 + lane];            \
    float mu_ = fs_ * 0.015625f;                                          \
    float inv_ = rsqrtf(fq_ * 0.015625f - mu_ * mu_ + 1e-6f);             \
    _Pragma("unroll") for (int j = 0; j < 16; ++j) {                      \
        int c_ = c0 + j;                                                  \
        float hv_ = (xr[j] - mu_) * inv_ * (GPTR)[c_] + (BPTR)[c_];       \
        STORE;                                                            \
    }                                                                     \
    __syncthreads();                                                      \
} while (0)

__global__ void __launch_bounds__(256, 4) fsa_kernel(
    const int* __restrict__ tok,
    const float* __restrict__ emb, const float* __restrict__ np_w, const float* __restrict__ np_b,
    const float* __restrict__ grp_wq, const float* __restrict__ grp_bq,
    const float* __restrict__ grp_wk, const float* __restrict__ grp_bk,
    const float* __restrict__ grp_ln_g, const float* __restrict__ grp_ln_b,
    const float* __restrict__ attn_w, const float* __restrict__ attn_b,
    const float* __restrict__ ln1_g, const float* __restrict__ ln1_b,
    const float* __restrict__ ln2_g, const float* __restrict__ ln2_b,
    const float* __restrict__ ffn_w1, const float* __restrict__ ffn_b1,
    const float* __restrict__ ffn_w2, const float* __restrict__ ffn_b2,
    const float* __restrict__ enc_g, const float* __restrict__ enc_b,
    const float* __restrict__ red_w, const float* __restrict__ red_b,
    const float* __restrict__ opc_w, const float* __restrict__ opc_b,
    const float* __restrict__ res_w, const float* __restrict__ res_b,
    float* __restrict__ out)
{
    __shared__ __align__(16) float lds[LDSN];
    const int b = blockIdx.x;
    const int tid = threadIdx.x;
    const int lane = tid & 63;
    const int wv = __builtin_amdgcn_readfirstlane(tid >> 6);
    const int c0 = wv << 4;
    const int wv4 = wv << 2;
    const int rl = tid >> 3;      // 0..31
    const int jg = tid & 7;       // score-col group: j = ju*8 + jg
    float xr[16];                 // x[lane][c0 .. c0+15] in registers

    // ================= embedding + positional encoding =================
    {
        int t = tok[(b << 6) + lane];
        float mk  = (t != 0) ? 1.f : 0.f;
        float isd = (t >= 4 && t <= 13) ? 1.f : 0.f;
        float dvv = ((float)t - 4.f) * isd;
        float iso = (t >= 14 && t <= 17) ? 1.f : 0.f;
        float opt = iso * ((float)t - 13.f);
        if (wv == 0) {
            lds[M_MASK + lane] = mk;  lds[M_DVAL + lane] = dvv; lds[M_ISD + lane] = isd;
            lds[M_PRU + lane] = 0.f;  lds[M_PRD + lane] = 0.f;
        }
        const float lg = -0.143911568f;   // -ln(10000)/64
        #pragma unroll
        for (int j = 0; j < 16; ++j) {
            int c = c0 + j;
            float freq = expf((float)(c & ~1) * lg);
            float ang = (float)lane * freq;
            float pe = (c & 1) ? cosf(ang) : sinf(ang);
            xr[j] = emb[t * 64 + c] * 8.f
                  + dvv * np_w[c] + isd * np_w[64 + c]
                  + opt * np_w[128 + c] + iso * np_w[192 + c]
                  + np_b[c] + pe;
        }
    }

    // ================= transformer layers =================
    for (int il = 0; il < 2; ++il) {
        const float* gwq = grp_wq + il * 4096; const float* gbq = grp_bq + (il << 6);
        const float* gwk = grp_wk + il * 4096; const float* gbk = grp_bk + (il << 6);
        const float* glg = grp_ln_g + (il << 6); const float* glb = grp_ln_b + (il << 6);
        const float* aw  = attn_w + il * 16384;  const float* ab  = attn_b + (il << 8);
        const float* l1g = ln1_g + (il << 6);    const float* l1b = ln1_b + (il << 6);
        const float* l2g = ln2_g + (il << 6);    const float* l2b = ln2_b + (il << 6);
        const float* fw1 = ffn_w1 + il * 8192;   const float* fb1 = ffn_b1 + (il << 7);
        const float* fw2 = ffn_w2 + il * 8192;   const float* fb2 = ffn_b2 + (il << 6);

        // ---- group (constituent) attention ----
        LN_STORE(glg, glb, lds[A + c_ * 64 + lane] = hv_);
        {   // fused gQ/gK GEMM streaming hT
            float qa[16], ka[16];
            #pragma unroll
            for (int j = 0; j < 16; ++j) { qa[j] = gbq[c0 + j]; ka[j] = gbk[c0 + j]; }
            #pragma unroll 8
            for (int kk = 0; kk < 64; ++kk) {
                float a = lds[A + kk * 64 + lane];
                const float* wq = gwq + kk * 64 + c0;
                const float* wk = gwk + kk * 64 + c0;
                #pragma unroll
                for (int j = 0; j < 16; ++j) {
                    qa[j] = fmaf(a, wq[j], qa[j]);
                    ka[j] = fmaf(a, wk[j], ka[j]);
                }
            }
            #pragma unroll
            for (int j = 0; j < 16; ++j) lds[Bb + (c0 + j) * 64 + lane] = qa[j]; // gQ^T
            __syncthreads();          // hT reads done; gQ^T visible
            #pragma unroll
            for (int j = 0; j < 16; ++j) lds[A + (c0 + j) * 64 + lane] = ka[j];  // gK^T
            __syncthreads();
        }

        if (tid < 126) {              // s[i,i+1] and s[i+1,i]
            int i = tid >> 1, w = tid & 1;
            int ra = w ? i + 1 : i, rb = w ? i : i + 1;
            float s = 0.f;
            #pragma unroll 8
            for (int c2 = 0; c2 < 64; ++c2)
                s = fmaf(lds[Bb + c2 * 64 + ra], lds[A + c2 * 64 + rb], s);
            lds[(w ? M_SDN : M_SU) + i] = s * 0.125f;   // / sqrt(H)
        }
        __syncthreads();

        if (wv == 0) {   // merged: masked softmax + symmetrize + prior + shfl scan
            const int i = lane;
            float mi  = lds[M_MASK + i];
            float mup = (i < 63) ? lds[M_MASK + i + 1] : 0.f;
            float mdn = (i > 0)  ? lds[M_MASK + i - 1] : 0.f;
            float eu = (mi > 0.f && mup > 0.f) ? lds[M_SU + i] : -1e9f;
            float ed = (i > 0 && mi > 0.f && mdn > 0.f) ? lds[M_SDN + i - 1] : -1e9f;
            float m = fmaxf(eu, ed);
            float nu, nd, ng;
            if (m <= -1e9f) { nu = 0.015625f; nd = 0.015625f; ng = 0.015625f; }
            else {
                float zu = __expf(eu - m), zd = __expf(ed - m);
                float iz = 1.f / (zu + zd);
                nu = zu * iz; nd = zd * iz; ng = 0.f;
            }
            float nd1 = __shfl_down(nd, 1);       // nb_dn of row i+1
            float pd = lds[M_PRD + i];
            float dsym = sqrtf(ng * ng + 1e-9f);
            float d2 = pd + (1.f - pd) * dsym;
            lds[M_DVEC + i] = d2; lds[M_PRD + i] = d2;
            float la = 0.f;
            if (i < 63) {
                float pu = lds[M_PRU + i];
                float as_ = sqrtf(nu * nd1 + 1e-9f);
                float a2 = pu + (1.f - pu) * as_;
                la = logf(a2 + 1e-9f);
                lds[M_PRU + i] = __expf(la) + 1e-9f;   // next-layer prior
            }
            float x = __shfl_up(la, 1);
            if (i == 0) x = 0.f;
            #pragma unroll
            for (int off = 1; off < 64; off <<= 1) {
                float t2 = __shfl_up(x, off);
                if (i >= off) x += t2;
            }
            lds[M_S + i] = x;                     // S[i] = sum_{k<i} la[k]
        }
        __syncthreads();

        // ---- multi-head attention, weighted by g (heads outer) ----
        LN_STORE(l1g, l1b, lds[A + c_ * 64 + lane] = hv_);
        for (int hh = 0; hh < 4; ++hh) {
            const int hb = hh << 4;
            // per-head QKV GEMM: this thread owns 4 cols of each
            float q4[4], k4[4], v4[4];
            #pragma unroll
            for (int j = 0; j < 4; ++j) {
                q4[j] = ab[hb + wv4 + j];
                k4[j] = ab[64 + hb + wv4 + j];
                v4[j] = ab[128 + hb + wv4 + j];
            }
            #pragma unroll 8
            for (int kk = 0; kk < 64; ++kk) {
                float a = lds[A + kk * 64 + lane];
                const float* wq  = aw + kk * 64 + hb + wv4;
                const float* wk  = aw + 4096 + kk * 64 + hb + wv4;
                const float* wvp = aw + 8192 + kk * 64 + hb + wv4;
                #pragma unroll
                for (int j = 0; j < 4; ++j) {
                    q4[j] = fmaf(a, wq[j], q4[j]);
                    k4[j] = fmaf(a, wk[j], k4[j]);
                    v4[j] = fmaf(a, wvp[j], v4[j]);
                }
            }
            __syncthreads();          // prev head's B reads done
            *reinterpret_cast<float4*>(&lds[QH + lane * 20 + wv4]) = make_float4(q4[0], q4[1], q4[2], q4[3]);
            *reinterpret_cast<float4*>(&lds[KH + lane * 20 + wv4]) = make_float4(k4[0], k4[1], k4[2], k4[3]);
            *reinterpret_cast<float4*>(&lds[VH + lane * 20 + wv4]) = make_float4(v4[0], v4[1], v4[2], v4[3]);
            __syncthreads();

            // q rows rl and rl+32 (8-lane broadcast, conflict-free)
            float q0[16], q1[16];
            #pragma unroll
            for (int c4 = 0; c4 < 4; ++c4) {
                float4 a0 = *reinterpret_cast<const float4*>(&lds[QH + rl * 20 + (c4 << 2)]);
                float4 a1 = *reinterpret_cast<const float4*>(&lds[QH + (rl + 32) * 20 + (c4 << 2)]);
                q0[(c4<<2)+0] = a0.x; q0[(c4<<2)+1] = a0.y; q0[(c4<<2)+2] = a0.z; q0[(c4<<2)+3] = a0.w;
                q1[(c4<<2)+0] = a1.x; q1[(c4<<2)+1] = a1.y; q1[(c4<<2)+2] = a1.z; q1[(c4<<2)+3] = a1.w;
            }
            float sc0[8], sc1[8];
            #pragma unroll
            for (int ju = 0; ju < 8; ++ju) {
                float s0 = 0.f, s1 = 0.f;
                #pragma unroll
                for (int c4 = 0; c4 < 4; ++c4) {
                    const float4 kv = *reinterpret_cast<const float4*>(
                        &lds[KH + (ju * 8 + jg) * 20 + (c4 << 2)]);
                    s0 = fmaf(q0[(c4<<2)+0], kv.x, s0); s0 = fmaf(q0[(c4<<2)+1], kv.y, s0);
                    s0 = fmaf(q0[(c4<<2)+2], kv.z, s0); s0 = fmaf(q0[(c4<<2)+3], kv.w, s0);
                    s1 = fmaf(q1[(c4<<2)+0], kv.x, s1); s1 = fmaf(q1[(c4<<2)+1], kv.y, s1);
                    s1 = fmaf(q1[(c4<<2)+2], kv.z, s1); s1 = fmaf(q1[(c4<<2)+3], kv.w, s1);
                }
                sc0[ju] = s0; sc1[ju] = s1;
            }
            float m0 = -1e9f, m1 = -1e9f;
            #pragma unroll
            for (int ju = 0; ju < 8; ++ju) {
                float mk = lds[M_MASK + ju * 8 + jg];
                sc0[ju] = (mk > 0.f) ? sc0[ju] * 0.25f : -1e9f;
                sc1[ju] = (mk > 0.f) ? sc1[ju] * 0.25f : -1e9f;
                m0 = fmaxf(m0, sc0[ju]); m1 = fmaxf(m1, sc1[ju]);
            }
            m0 = fmaxf(m0, __shfl_xor(m0, 1)); m0 = fmaxf(m0, __shfl_xor(m0, 2)); m0 = fmaxf(m0, __shfl_xor(m0, 4));
            m1 = fmaxf(m1, __shfl_xor(m1, 1)); m1 = fmaxf(m1, __shfl_xor(m1, 2)); m1 = fmaxf(m1, __shfl_xor(m1, 4));
            float z0 = 0.f, z1 = 0.f;
            float p0[8], p1[8];
            #pragma unroll
            for (int ju = 0; ju < 8; ++ju) {
                p0[ju] = __expf(sc0[ju] - m0); z0 += p0[ju];
                p1[ju] = __expf(sc1[ju] - m1); z1 += p1[ju];
            }
            z0 += __shfl_xor(z0, 1); z0 += __shfl_xor(z0, 2); z0 += __shfl_xor(z0, 4);
            z1 += __shfl_xor(z1, 1); z1 += __shfl_xor(z1, 2); z1 += __shfl_xor(z1, 4);
            float iz0 = 1.f / z0, iz1 = 1.f / z1;
            float Sr0 = lds[M_S + rl], Sr1 = lds[M_S + rl + 32];
            float dv0 = lds[M_DVEC + rl], dv1 = lds[M_DVEC + rl + 32];
            #pragma unroll
            for (int ju = 0; ju < 8; ++ju) {
                int jj = ju * 8 + jg;
                float Sj = lds[M_S + jj];
                float g0 = (jj == rl)      ? dv0 : (__expf((jj > rl)      ? (Sj - Sr0) : (Sr0 - Sj)) + 1e-9f);
                float g1 = (jj == rl + 32) ? dv1 : (__expf((jj > rl + 32) ? (Sj - Sr1) : (Sr1 - Sj)) + 1e-9f);
                p0[ju] = p0[ju] * iz0 * g0;
                p1[ju] = p1[ju] * iz1 * g1;
            }
            float po0[16], po1[16];
            #pragma unroll
            for (int c = 0; c < 16; ++c) { po0[c] = 0.f; po1[c] = 0.f; }
            #pragma unroll
            for (int ju = 0; ju < 8; ++ju) {
                #pragma unroll
                for (int c4 = 0; c4 < 4; ++c4) {
                    const float4 v = *reinterpret_cast<const float4*>(
                        &lds[VH + (ju * 8 + jg) * 20 + (c4 << 2)]);
                    po0[(c4<<2)+0] = fmaf(p0[ju], v.x, po0[(c4<<2)+0]);
                    po0[(c4<<2)+1] = fmaf(p0[ju], v.y, po0[(c4<<2)+1]);
                    po0[(c4<<2)+2] = fmaf(p0[ju], v.z, po0[(c4<<2)+2]);
                    po0[(c4<<2)+3] = fmaf(p0[ju], v.w, po0[(c4<<2)+3]);
                    po1[(c4<<2)+0] = fmaf(p1[ju], v.x, po1[(c4<<2)+0]);
                    po1[(c4<<2)+1] = fmaf(p1[ju], v.y, po1[(c4<<2)+1]);
                    po1[(c4<<2)+2] = fmaf(p1[ju], v.z, po1[(c4<<2)+2]);
                    po1[(c4<<2)+3] = fmaf(p1[ju], v.w, po1[(c4<<2)+3]);
                }
            }
            #pragma unroll
            for (int c = 0; c < 16; ++c) {
                po0[c] += __shfl_xor(po0[c], 1); po0[c] += __shfl_xor(po0[c], 2); po0[c] += __shfl_xor(po0[c], 4);
                po1[c] += __shfl_xor(po1[c], 1); po1[c] += __shfl_xor(po1[c], 2); po1[c] += __shfl_xor(po1[c], 4);
            }
            __syncthreads();          // QH/KH/VH reads done
            if (jg == 0) {            // O_h overwrites QH
                #pragma unroll
                for (int c4 = 0; c4 < 4; ++c4) {
                    *reinterpret_cast<float4*>(&lds[QH + rl * 20 + (c4 << 2)]) =
                        make_float4(po0[(c4<<2)+0], po0[(c4<<2)+1], po0[(c4<<2)+2], po0[(c4<<2)+3]);
                    *reinterpret_cast<float4*>(&lds[QH + (rl + 32) * 20 + (c4 << 2)]) =
                        make_float4(po1[(c4<<2)+0], po1[(c4<<2)+1], po1[(c4<<2)+2], po1[(c4<<2)+3]);
                }
            }
            __syncthreads();
            // O-proj slice: xr += O_h @ Wo[hb:hb+16, :]
            {
                const float* Wo = aw + 12288; const float* bo = ab + 192;
                float oh[16];
                #pragma unroll
                for (int c4 = 0; c4 < 4; ++c4) {
                    float4 o4 = *reinterpret_cast<const float4*>(&lds[QH + lane * 20 + (c4 << 2)]);
                    oh[(c4<<2)+0] = o4.x; oh[(c4<<2)+1] = o4.y; oh[(c4<<2)+2] = o4.z; oh[(c4<<2)+3] = o4.w;
                }
                float acc[16];
                #pragma unroll
                for (int j = 0; j < 16; ++j) acc[j] = (hh == 0) ? bo[c0 + j] : 0.f;
                #pragma unroll
                for (int d = 0; d < 16; ++d) {
                    const float* wr = Wo + (hb + d) * 64 + c0;
                    #pragma unroll
                    for (int j = 0; j < 16; ++j) acc[j] = fmaf(oh[d], wr[j], acc[j]);
                }
                #pragma unroll
                for (int j = 0; j < 16; ++j) xr[j] += acc[j];
            }
        }

        // ---- FFN (two 64-col halves of F share one buffer) ----
        LN_STORE(l2g, l2b, lds[A + c_ * 64 + lane] = hv_);
        {   // F-lo
            float fa[16];
            #pragma unroll
            for (int j = 0; j < 16; ++j) fa[j] = fb1[c0 + j];
            #pragma unroll 8
            for (int kk = 0; kk < 64; ++kk) {
                float a = lds[A + kk * 64 + lane];
                const float* wr = fw1 + kk * 128 + c0;
                #pragma unroll
                for (int j = 0; j < 16; ++j) fa[j] = fmaf(a, wr[j], fa[j]);
            }
            #pragma unroll
            for (int j = 0; j < 16; ++j) lds[Bb + (c0 + j) * 64 + lane] = fmaxf(fa[j], 0.f);
        }
        __syncthreads();
        {   // xr += F-lo @ W2[0:64]
            float acc[16];
            #pragma unroll
            for (int j = 0; j < 16; ++j) acc[j] = fb2[c0 + j];
            #pragma unroll 8
            for (int kk = 0; kk < 64; ++kk) {
                float a = lds[Bb + kk * 64 + lane];
                const float* wr = fw2 + kk * 64 + c0;
                #pragma unroll
                for (int j = 0; j < 16; ++j) acc[j] = fmaf(a, wr[j], acc[j]);
            }
            #pragma unroll
            for (int j = 0; j < 16; ++j) xr[j] += acc[j];
        }
        __syncthreads();
        {   // F-hi
            float fa[16];
            #pragma unroll
            for (int j = 0; j < 16; ++j) fa[j] = fb1[64 + c0 + j];
            #pragma unroll 8
            for (int kk = 0; kk < 64; ++kk) {
                float a = lds[A + kk * 64 + lane];
                const float* wr = fw1 + kk * 128 + 64 + c0;
                #pragma unroll
                for (int j = 0; j < 16; ++j) fa[j] = fmaf(a, wr[j], fa[j]);
            }
            #pragma unroll
            for (int j = 0; j < 16; ++j) lds[Bb + (c0 + j) * 64 + lane] = fmaxf(fa[j], 0.f);
        }
        __syncthreads();
        {   // xr += F-hi @ W2[64:128]
            float acc[16];
            #pragma unroll
            for (int j = 0; j < 16; ++j) acc[j] = 0.f;
            #pragma unroll 8
            for (int kk = 0; kk < 64; ++kk) {
                float a = lds[Bb + kk * 64 + lane];
                const float* wr = fw2 + (64 + kk) * 64 + c0;
                #pragma unroll
                for (int j = 0; j < 16; ++j) acc[j] = fmaf(a, wr[j], acc[j]);
            }
            #pragma unroll
            for (int j = 0; j < 16; ++j) xr[j] += acc[j];
        }
        // next phase's LN barriers protect A/Bb reuse
    }

    // ================= reduction / calculator head =================
    LN_STORE(enc_g, enc_b, lds[Bb + lane * 65 + c_] = hv_);   // hR stride 65
    if (tid < 64) {       // scores = h @ red_w + red_b + (1-mask)*-1e9
        float s = 0.f;
        #pragma unroll 8
        for (int c2 = 0; c2 < 64; ++c2)
            s = fmaf(lds[Bb + tid * 65 + c2], red_w[c2], s);
        s += red_b[0];
        s += (1.f - lds[M_MASK + tid]) * -1e9f;
        lds[M_SU + tid] = s;
    }
    __syncthreads();

    if (wv == 0) {        // softmax, scans, digit assembly (wave 0)
        float s = lds[M_SU + lane];
        float m = s;
        #pragma unroll
        for (int off = 1; off < 64; off <<= 1) m = fmaxf(m, __shfl_xor(m, off));
        float ee = expf(s - m);
        float z = ee;
        #pragma unroll
        for (int off = 1; off < 64; off <<= 1) z += __shfl_xor(z, off);
        float rw = ee / z;
        lds[M_SD + lane] = rw;
        float cum = rw;
        #pragma unroll
        for (int off = 1; off < 64; off <<= 1) { float t2 = __shfl_up(cum, off); if (lane >= off) cum += t2; }
        float isd = lds[M_ISD + lane], dvv = lds[M_DVAL + lane];
        float lm = (1.f - cum) * isd;
        float rm = (cum - rw) * isd;
        float cl = lm;
        #pragma unroll
        for (int off = 1; off < 64; off <<= 1) { float t2 = __shfl_up(cl, off); if (lane >= off) cl += t2; }
        float totl = __shfl(cl, 63);
        float wL = powf(10.f, (totl - cl) * lm) * lm;
        float lv = dvv * wL;
        #pragma unroll
        for (int off = 1; off < 64; off <<= 1) lv += __shfl_xor(lv, off);
        float cr = rm;
        #pragma unroll
        for (int off = 1; off < 64; off <<= 1) { float t2 = __shfl_up(cr, off); if (lane >= off) cr += t2; }
        float totr = __shfl(cr, 63);
        float wR = powf(10.f, (totr - cr) * rm) * rm;
        float rv = dvv * wR;
        #pragma unroll
        for (int off = 1; off < 64; off <<= 1) rv += __shfl_xor(rv, off);
        if (lane == 0) { lds[M_DG + 2] = lv; lds[M_DG + 3] = rv; }
    }
    __syncthreads();

    if (tid < 64) {       // pooled[c] = sum_r h[r][c] * rw[r]
        float p = 0.f;
        #pragma unroll 8
        for (int r2 = 0; r2 < 64; ++r2)
            p = fmaf(lds[Bb + r2 * 65 + tid], lds[M_SD + r2], p);
        lds[M_NBU + tid] = p;
    }
    __syncthreads();
    if (tid < 4) {        // op logits
        float s = opc_b[tid];
        for (int c2 = 0; c2 < 64; ++c2) s = fmaf(lds[M_NBU + c2], opc_w[(c2 << 2) + tid], s);
        lds[M_DG + 4 + tid] = s;
    }
    __syncthreads();
    if (tid == 0) {       // hard argmax op select + fixed ops
        float l = lds[M_DG + 2], r = lds[M_DG + 3];
        float o0 = lds[M_DG + 4], o1 = lds[M_DG + 5], o2 = lds[M_DG + 6], o3 = lds[M_DG + 7];
        int op = 0; float bm = o0;
        if (o1 > bm) { bm = o1; op = 1; }
        if (o2 > bm) { bm = o2; op = 2; }
        if (o3 > bm) { bm = o3; op = 3; }
        float res, vl = 1.f;
        if (op == 0)      res = l + r;
        else if (op == 1) res = l - r;
        else if (op == 2) res = l * r;
        else { bool bad = fabsf(r) < 1e-6f; res = bad ? 0.f : (l / r); vl = bad ? 0.f : 1.f; }
        float rc = (res > 0.f) ? log1pf(res) : ((res < 0.f) ? -log1pf(-res) : 0.f);
        lds[M_DG + 0] = rc; lds[M_DG + 1] = vl;
        out[O_RES + b]   = res;
        out[O_VALID + b] = vl;
        out[O_LEFT + b]  = l;
        out[O_RIGHT + b] = r;
    }
    __syncthreads();
    if (tid < 64) {
        float rc = lds[M_DG + 0], vl = lds[M_DG + 1];
        out[O_REMB + (b << 6) + tid] = rc * res_w[tid] + vl * res_w[64 + tid] + res_b[tid];
        out[O_RW + (b << 6) + tid] = lds[M_SD + tid];
    }
    if (tid >= 64 && tid < 68) {
        int o = tid - 64;
        out[O_OPL + (b << 2) + o] = lds[M_DG + 4 + o];
    }
}

extern "C" void kernel_launch(void* const* d_in, const int* in_sizes, int n_in,
                              void* d_out, int out_size, void* d_ws, size_t ws_size,
                              hipStream_t stream)
{
    fsa_kernel<<<dim3(BATCH), dim3(256), 0, stream>>>(
        (const int*)d_in[0],
        (const float*)d_in[1],  (const float*)d_in[2],  (const float*)d_in[3],
        (const float*)d_in[4],  (const float*)d_in[5],  (const float*)d_in[6],  (const float*)d_in[7],
        (const float*)d_in[8],  (const float*)d_in[9],  (const float*)d_in[10], (const float*)d_in[11],
        (const float*)d_in[12], (const float*)d_in[13], (const float*)d_in[14], (const float*)d_in[15],
        (const float*)d_in[16], (const float*)d_in[17], (const float*)d_in[18], (const float*)d_in[19],
        (const float*)d_in[20], (const float*)d_in[21], (const float*)d_in[22], (const float*)d_in[23],
        (const float*)d_in[24], (const float*)d_in[25], (const float*)d_in[26], (const float*)d_in[27],
        (float*)d_out);
}

// Round 6
// 1444.144 us; speedup vs baseline: 4.3765x; 1.2802x over previous
//
#include <hip/hip_runtime.h>
#include <math.h>

// B=4096, L=64, H=64, V=21, NH=4, HD=16, FF=128, NL=2
constexpr int BATCH = 4096;

// ---------------- LDS regions (float indices), total 39,936 B -> 4 blocks/CU
// A  [0,4352):    hT [c][r] stride 64  /  gK^T stride 64
// Bb [4352,8704): gQ^T stride 64 / {QH,KH,VH 64x20} / F^T stride 64 / hR stride 65
// M  [8704,9984): masks, scan state, LN partials
constexpr int A    = 0;
constexpr int Bb   = 4352;
constexpr int QH   = Bb;            // 64x20
constexpr int KH   = Bb + 1280;     // 64x20
constexpr int VH   = Bb + 2560;     // 64x20
constexpr int MB   = 8704;
constexpr int M_MASK = MB + 0;
constexpr int M_DVAL = MB + 64;
constexpr int M_ISD  = MB + 128;
constexpr int M_SD   = MB + 192;    // final rw
constexpr int M_NBU  = MB + 256;    // pooled
constexpr int M_DG   = MB + 320;    // scalars
constexpr int M_DVEC = MB + 384;    // g diagonal
constexpr int M_S    = MB + 448;    // prefix sums
constexpr int M_PRU  = MB + 512;    // prior g[i,i+1]
constexpr int M_PRD  = MB + 576;    // prior g[i,i]
constexpr int M_SU   = MB + 640;    // s_up
constexpr int M_SDN  = MB + 704;    // s_dn
constexpr int PS     = MB + 768;    // 4x64 LN partial sums
constexpr int PSQ    = MB + 1024;   // 4x64 LN partial sumsq
constexpr int LDSN   = MB + 1280;   // 9984 floats = 39,936 B

// ---------------- output layout (floats) ----------------
constexpr int O_RES   = 0;
constexpr int O_REMB  = 4096;
constexpr int O_VALID = 266240;
constexpr int O_LEFT  = 270336;
constexpr int O_RIGHT = 274432;
constexpr int O_OPL   = 278528;
constexpr int O_RW    = 294912;

// LN of xr; stats via 4-wave LDS partial reduce; then STORE per column.
#define LN_STORE(GPTR, BPTR, STORE) do {                                  \
    float s_ = 0.f, q_ = 0.f;                                             \
    _Pragma("unroll") for (int j = 0; j < 16; ++j) {                      \
        s_ += xr[j]; q_ = fmaf(xr[j], xr[j], q_); }                       \
    lds[PS  + (wv << 6) + lane] = s_;                                     \
    lds[PSQ + (wv << 6) + lane] = q_;                                     \
    __syncthreads();                                                      \
    float fs_ = lds[PS + lane] + lds[PS + 64 + lane]                      \
              + lds[PS + 128 + lane] + lds[PS + 192 + lane];              \
    float fq_ = lds[PSQ + lane] + lds[PSQ + 64 + lane]                    \
              + lds[PSQ + 128 + lane] + lds[PSQ + 192 + lane];            \
    float mu_ = fs_ * 0.015625f;                                          \
    float inv_ = rsqrtf(fq_ * 0.015625f - mu_ * mu_ + 1e-6f);             \
    _Pragma("unroll") for (int j = 0; j < 16; ++j) {                      \
        int c_ = c0 + j;                                                  \
        float hv_ = (xr[j] - mu_) * inv_ * (GPTR)[c_] + (BPTR)[c_];       \
        STORE;                                                            \
    }                                                                     \
    __syncthreads();                                                      \
} while (0)

__global__ void __launch_bounds__(256, 2) fsa_kernel(
    const int* __restrict__ tok,
    const float* __restrict__ emb, const float* __restrict__ np_w, const float* __restrict__ np_b,
    const float* __restrict__ grp_wq, const float* __restrict__ grp_bq,
    const float* __restrict__ grp_wk, const float* __restrict__ grp_bk,
    const float* __restrict__ grp_ln_g, const float* __restrict__ grp_ln_b,
    const float* __restrict__ attn_w, const float* __restrict__ attn_b,
    const float* __restrict__ ln1_g, const float* __restrict__ ln1_b,
    const float* __restrict__ ln2_g, const float* __restrict__ ln2_b,
    const float* __restrict__ ffn_w1, const float* __restrict__ ffn_b1,
    const float* __restrict__ ffn_w2, const float* __restrict__ ffn_b2,
    const float* __restrict__ enc_g, const float* __restrict__ enc_b,
    const float* __restrict__ red_w, const float* __restrict__ red_b,
    const float* __restrict__ opc_w, const float* __restrict__ opc_b,
    const float* __restrict__ res_w, const float* __restrict__ res_b,
    float* __restrict__ out)
{
    __shared__ __align__(16) float lds[LDSN];
    const int b = blockIdx.x;
    const int tid = threadIdx.x;
    const int lane = tid & 63;
    const int wv = __builtin_amdgcn_readfirstlane(tid >> 6);
    const int c0 = wv << 4;
    const int wv4 = wv << 2;
    const int rl = tid >> 3;      // 0..31
    const int jg = tid & 7;       // score-col group: j = ju*8 + jg
    float xr[16];                 // x[lane][c0 .. c0+15] in registers

    // ================= embedding + positional encoding =================
    {
        int t = tok[(b << 6) + lane];
        float mk  = (t != 0) ? 1.f : 0.f;
        float isd = (t >= 4 && t <= 13) ? 1.f : 0.f;
        float dvv = ((float)t - 4.f) * isd;
        float iso = (t >= 14 && t <= 17) ? 1.f : 0.f;
        float opt = iso * ((float)t - 13.f);
        if (wv == 0) {
            lds[M_MASK + lane] = mk;  lds[M_DVAL + lane] = dvv; lds[M_ISD + lane] = isd;
            lds[M_PRU + lane] = 0.f;  lds[M_PRD + lane] = 0.f;
        }
        const float lg = -0.143911568f;   // -ln(10000)/64
        #pragma unroll
        for (int j = 0; j < 16; ++j) {
            int c = c0 + j;
            float freq = expf((float)(c & ~1) * lg);
            float ang = (float)lane * freq;
            float pe = (c & 1) ? cosf(ang) : sinf(ang);
            xr[j] = emb[t * 64 + c] * 8.f
                  + dvv * np_w[c] + isd * np_w[64 + c]
                  + opt * np_w[128 + c] + iso * np_w[192 + c]
                  + np_b[c] + pe;
        }
    }

    // ================= transformer layers =================
    for (int il = 0; il < 2; ++il) {
        const float* gwq = grp_wq + il * 4096; const float* gbq = grp_bq + (il << 6);
        const float* gwk = grp_wk + il * 4096; const float* gbk = grp_bk + (il << 6);
        const float* glg = grp_ln_g + (il << 6); const float* glb = grp_ln_b + (il << 6);
        const float* aw  = attn_w + il * 16384;  const float* ab  = attn_b + (il << 8);
        const float* l1g = ln1_g + (il << 6);    const float* l1b = ln1_b + (il << 6);
        const float* l2g = ln2_g + (il << 6);    const float* l2b = ln2_b + (il << 6);
        const float* fw1 = ffn_w1 + il * 8192;   const float* fb1 = ffn_b1 + (il << 7);
        const float* fw2 = ffn_w2 + il * 8192;   const float* fb2 = ffn_b2 + (il << 6);

        // ---- group (constituent) attention ----
        LN_STORE(glg, glb, lds[A + c_ * 64 + lane] = hv_);
        {   // fused gQ/gK GEMM streaming hT
            float qa[16], ka[16];
            #pragma unroll
            for (int j = 0; j < 16; ++j) { qa[j] = gbq[c0 + j]; ka[j] = gbk[c0 + j]; }
            #pragma unroll 8
            for (int kk = 0; kk < 64; ++kk) {
                float a = lds[A + kk * 64 + lane];
                const float* wq = gwq + kk * 64 + c0;
                const float* wk = gwk + kk * 64 + c0;
                #pragma unroll
                for (int j = 0; j < 16; ++j) {
                    qa[j] = fmaf(a, wq[j], qa[j]);
                    ka[j] = fmaf(a, wk[j], ka[j]);
                }
            }
            #pragma unroll
            for (int j = 0; j < 16; ++j) lds[Bb + (c0 + j) * 64 + lane] = qa[j]; // gQ^T
            __syncthreads();          // hT reads done; gQ^T visible
            #pragma unroll
            for (int j = 0; j < 16; ++j) lds[A + (c0 + j) * 64 + lane] = ka[j];  // gK^T
            __syncthreads();
        }

        if (tid < 126) {              // s[i,i+1] and s[i+1,i]
            int i = tid >> 1, w = tid & 1;
            int ra = w ? i + 1 : i, rb = w ? i : i + 1;
            float s = 0.f;
            #pragma unroll 8
            for (int c2 = 0; c2 < 64; ++c2)
                s = fmaf(lds[Bb + c2 * 64 + ra], lds[A + c2 * 64 + rb], s);
            lds[(w ? M_SDN : M_SU) + i] = s * 0.125f;   // / sqrt(H)
        }
        __syncthreads();

        if (wv == 0) {   // merged: masked softmax + symmetrize + prior + shfl scan
            const int i = lane;
            float mi  = lds[M_MASK + i];
            float mup = (i < 63) ? lds[M_MASK + i + 1] : 0.f;
            float mdn = (i > 0)  ? lds[M_MASK + i - 1] : 0.f;
            float eu = (mi > 0.f && mup > 0.f) ? lds[M_SU + i] : -1e9f;
            float ed = (i > 0 && mi > 0.f && mdn > 0.f) ? lds[M_SDN + i - 1] : -1e9f;
            float m = fmaxf(eu, ed);
            float nu, nd, ng;
            if (m <= -1e9f) { nu = 0.015625f; nd = 0.015625f; ng = 0.015625f; }
            else {
                float zu = __expf(eu - m), zd = __expf(ed - m);
                float iz = 1.f / (zu + zd);
                nu = zu * iz; nd = zd * iz; ng = 0.f;
            }
            float nd1 = __shfl_down(nd, 1);       // nb_dn of row i+1
            float pd = lds[M_PRD + i];
            float dsym = sqrtf(ng * ng + 1e-9f);
            float d2 = pd + (1.f - pd) * dsym;
            lds[M_DVEC + i] = d2; lds[M_PRD + i] = d2;
            float la = 0.f;
            if (i < 63) {
                float pu = lds[M_PRU + i];
                float as_ = sqrtf(nu * nd1 + 1e-9f);
                float a2 = pu + (1.f - pu) * as_;
                la = logf(a2 + 1e-9f);
                lds[M_PRU + i] = __expf(la) + 1e-9f;   // next-layer prior
            }
            float x = __shfl_up(la, 1);
            if (i == 0) x = 0.f;
            #pragma unroll
            for (int off = 1; off < 64; off <<= 1) {
                float t2 = __shfl_up(x, off);
                if (i >= off) x += t2;
            }
            lds[M_S + i] = x;                     // S[i] = sum_{k<i} la[k]
        }
        __syncthreads();

        // ---- multi-head attention, weighted by g (heads outer) ----
        LN_STORE(l1g, l1b, lds[A + c_ * 64 + lane] = hv_);
        for (int hh = 0; hh < 4; ++hh) {
            const int hb = hh << 4;
            // per-head QKV GEMM: this thread owns 4 cols of each
            float q4[4], k4[4], v4[4];
            #pragma unroll
            for (int j = 0; j < 4; ++j) {
                q4[j] = ab[hb + wv4 + j];
                k4[j] = ab[64 + hb + wv4 + j];
                v4[j] = ab[128 + hb + wv4 + j];
            }
            #pragma unroll 8
            for (int kk = 0; kk < 64; ++kk) {
                float a = lds[A + kk * 64 + lane];
                const float* wq  = aw + kk * 64 + hb + wv4;
                const float* wk  = aw + 4096 + kk * 64 + hb + wv4;
                const float* wvp = aw + 8192 + kk * 64 + hb + wv4;
                #pragma unroll
                for (int j = 0; j < 4; ++j) {
                    q4[j] = fmaf(a, wq[j], q4[j]);
                    k4[j] = fmaf(a, wk[j], k4[j]);
                    v4[j] = fmaf(a, wvp[j], v4[j]);
                }
            }
            __syncthreads();          // prev head's B reads done
            *reinterpret_cast<float4*>(&lds[QH + lane * 20 + wv4]) = make_float4(q4[0], q4[1], q4[2], q4[3]);
            *reinterpret_cast<float4*>(&lds[KH + lane * 20 + wv4]) = make_float4(k4[0], k4[1], k4[2], k4[3]);
            *reinterpret_cast<float4*>(&lds[VH + lane * 20 + wv4]) = make_float4(v4[0], v4[1], v4[2], v4[3]);
            __syncthreads();

            // q rows rl and rl+32 (8-lane broadcast, conflict-free)
            float q0[16], q1[16];
            #pragma unroll
            for (int c4 = 0; c4 < 4; ++c4) {
                float4 a0 = *reinterpret_cast<const float4*>(&lds[QH + rl * 20 + (c4 << 2)]);
                float4 a1 = *reinterpret_cast<const float4*>(&lds[QH + (rl + 32) * 20 + (c4 << 2)]);
                q0[(c4<<2)+0] = a0.x; q0[(c4<<2)+1] = a0.y; q0[(c4<<2)+2] = a0.z; q0[(c4<<2)+3] = a0.w;
                q1[(c4<<2)+0] = a1.x; q1[(c4<<2)+1] = a1.y; q1[(c4<<2)+2] = a1.z; q1[(c4<<2)+3] = a1.w;
            }
            float sc0[8], sc1[8];
            #pragma unroll
            for (int ju = 0; ju < 8; ++ju) {
                float s0 = 0.f, s1 = 0.f;
                #pragma unroll
                for (int c4 = 0; c4 < 4; ++c4) {
                    const float4 kv = *reinterpret_cast<const float4*>(
                        &lds[KH + (ju * 8 + jg) * 20 + (c4 << 2)]);
                    s0 = fmaf(q0[(c4<<2)+0], kv.x, s0); s0 = fmaf(q0[(c4<<2)+1], kv.y, s0);
                    s0 = fmaf(q0[(c4<<2)+2], kv.z, s0); s0 = fmaf(q0[(c4<<2)+3], kv.w, s0);
                    s1 = fmaf(q1[(c4<<2)+0], kv.x, s1); s1 = fmaf(q1[(c4<<2)+1], kv.y, s1);
                    s1 = fmaf(q1[(c4<<2)+2], kv.z, s1); s1 = fmaf(q1[(c4<<2)+3], kv.w, s1);
                }
                sc0[ju] = s0; sc1[ju] = s1;
            }
            float m0 = -1e9f, m1 = -1e9f;
            #pragma unroll
            for (int ju = 0; ju < 8; ++ju) {
                float mk = lds[M_MASK + ju * 8 + jg];
                sc0[ju] = (mk > 0.f) ? sc0[ju] * 0.25f : -1e9f;
                sc1[ju] = (mk > 0.f) ? sc1[ju] * 0.25f : -1e9f;
                m0 = fmaxf(m0, sc0[ju]); m1 = fmaxf(m1, sc1[ju]);
            }
            m0 = fmaxf(m0, __shfl_xor(m0, 1)); m0 = fmaxf(m0, __shfl_xor(m0, 2)); m0 = fmaxf(m0, __shfl_xor(m0, 4));
            m1 = fmaxf(m1, __shfl_xor(m1, 1)); m1 = fmaxf(m1, __shfl_xor(m1, 2)); m1 = fmaxf(m1, __shfl_xor(m1, 4));
            float z0 = 0.f, z1 = 0.f;
            float p0[8], p1[8];
            #pragma unroll
            for (int ju = 0; ju < 8; ++ju) {
                p0[ju] = __expf(sc0[ju] - m0); z0 += p0[ju];
                p1[ju] = __expf(sc1[ju] - m1); z1 += p1[ju];
            }
            z0 += __shfl_xor(z0, 1); z0 += __shfl_xor(z0, 2); z0 += __shfl_xor(z0, 4);
            z1 += __shfl_xor(z1, 1); z1 += __shfl_xor(z1, 2); z1 += __shfl_xor(z1, 4);
            float iz0 = 1.f / z0, iz1 = 1.f / z1;
            float Sr0 = lds[M_S + rl], Sr1 = lds[M_S + rl + 32];
            float dv0 = lds[M_DVEC + rl], dv1 = lds[M_DVEC + rl + 32];
            #pragma unroll
            for (int ju = 0; ju < 8; ++ju) {
                int jj = ju * 8 + jg;
                float Sj = lds[M_S + jj];
                float g0 = (jj == rl)      ? dv0 : (__expf((jj > rl)      ? (Sj - Sr0) : (Sr0 - Sj)) + 1e-9f);
                float g1 = (jj == rl + 32) ? dv1 : (__expf((jj > rl + 32) ? (Sj - Sr1) : (Sr1 - Sj)) + 1e-9f);
                p0[ju] = p0[ju] * iz0 * g0;
                p1[ju] = p1[ju] * iz1 * g1;
            }
            float po0[16], po1[16];
            #pragma unroll
            for (int c = 0; c < 16; ++c) { po0[c] = 0.f; po1[c] = 0.f; }
            #pragma unroll
            for (int ju = 0; ju < 8; ++ju) {
                #pragma unroll
                for (int c4 = 0; c4 < 4; ++c4) {
                    const float4 v = *reinterpret_cast<const float4*>(
                        &lds[VH + (ju * 8 + jg) * 20 + (c4 << 2)]);
                    po0[(c4<<2)+0] = fmaf(p0[ju], v.x, po0[(c4<<2)+0]);
                    po0[(c4<<2)+1] = fmaf(p0[ju], v.y, po0[(c4<<2)+1]);
                    po0[(c4<<2)+2] = fmaf(p0[ju], v.z, po0[(c4<<2)+2]);
                    po0[(c4<<2)+3] = fmaf(p0[ju], v.w, po0[(c4<<2)+3]);
                    po1[(c4<<2)+0] = fmaf(p1[ju], v.x, po1[(c4<<2)+0]);
                    po1[(c4<<2)+1] = fmaf(p1[ju], v.y, po1[(c4<<2)+1]);
                    po1[(c4<<2)+2] = fmaf(p1[ju], v.z, po1[(c4<<2)+2]);
                    po1[(c4<<2)+3] = fmaf(p1[ju], v.w, po1[(c4<<2)+3]);
                }
            }
            #pragma unroll
            for (int c = 0; c < 16; ++c) {
                po0[c] += __shfl_xor(po0[c], 1); po0[c] += __shfl_xor(po0[c], 2); po0[c] += __shfl_xor(po0[c], 4);
                po1[c] += __shfl_xor(po1[c], 1); po1[c] += __shfl_xor(po1[c], 2); po1[c] += __shfl_xor(po1[c], 4);
            }
            __syncthreads();          // QH/KH/VH reads done
            if (jg == 0) {            // O_h overwrites QH
                #pragma unroll
                for (int c4 = 0; c4 < 4; ++c4) {
                    *reinterpret_cast<float4*>(&lds[QH + rl * 20 + (c4 << 2)]) =
                        make_float4(po0[(c4<<2)+0], po0[(c4<<2)+1], po0[(c4<<2)+2], po0[(c4<<2)+3]);
                    *reinterpret_cast<float4*>(&lds[QH + (rl + 32) * 20 + (c4 << 2)]) =
                        make_float4(po1[(c4<<2)+0], po1[(c4<<2)+1], po1[(c4<<2)+2], po1[(c4<<2)+3]);
                }
            }
            __syncthreads();
            // O-proj slice: xr += O_h @ Wo[hb:hb+16, :]
            {
                const float* Wo = aw + 12288; const float* bo = ab + 192;
                float oh[16];
                #pragma unroll
                for (int c4 = 0; c4 < 4; ++c4) {
                    float4 o4 = *reinterpret_cast<const float4*>(&lds[QH + lane * 20 + (c4 << 2)]);
                    oh[(c4<<2)+0] = o4.x; oh[(c4<<2)+1] = o4.y; oh[(c4<<2)+2] = o4.z; oh[(c4<<2)+3] = o4.w;
                }
                float acc[16];
                #pragma unroll
                for (int j = 0; j < 16; ++j) acc[j] = (hh == 0) ? bo[c0 + j] : 0.f;
                #pragma unroll
                for (int d = 0; d < 16; ++d) {
                    const float* wr = Wo + (hb + d) * 64 + c0;
                    #pragma unroll
                    for (int j = 0; j < 16; ++j) acc[j] = fmaf(oh[d], wr[j], acc[j]);
                }
                #pragma unroll
                for (int j = 0; j < 16; ++j) xr[j] += acc[j];
            }
        }

        // ---- FFN (two 64-col halves of F share one buffer) ----
        LN_STORE(l2g, l2b, lds[A + c_ * 64 + lane] = hv_);
        {   // F-lo
            float fa[16];
            #pragma unroll
            for (int j = 0; j < 16; ++j) fa[j] = fb1[c0 + j];
            #pragma unroll 8
            for (int kk = 0; kk < 64; ++kk) {
                float a = lds[A + kk * 64 + lane];
                const float* wr = fw1 + kk * 128 + c0;
                #pragma unroll
                for (int j = 0; j < 16; ++j) fa[j] = fmaf(a, wr[j], fa[j]);
            }
            #pragma unroll
            for (int j = 0; j < 16; ++j) lds[Bb + (c0 + j) * 64 + lane] = fmaxf(fa[j], 0.f);
        }
        __syncthreads();
        {   // xr += F-lo @ W2[0:64]
            float acc[16];
            #pragma unroll
            for (int j = 0; j < 16; ++j) acc[j] = fb2[c0 + j];
            #pragma unroll 8
            for (int kk = 0; kk < 64; ++kk) {
                float a = lds[Bb + kk * 64 + lane];
                const float* wr = fw2 + kk * 64 + c0;
                #pragma unroll
                for (int j = 0; j < 16; ++j) acc[j] = fmaf(a, wr[j], acc[j]);
            }
            #pragma unroll
            for (int j = 0; j < 16; ++j) xr[j] += acc[j];
        }
        __syncthreads();
        {   // F-hi
            float fa[16];
            #pragma unroll
            for (int j = 0; j < 16; ++j) fa[j] = fb1[64 + c0 + j];
            #pragma unroll 8
            for (int kk = 0; kk < 64; ++kk) {
                float a = lds[A + kk * 64 + lane];
                const float* wr = fw1 + kk * 128 + 64 + c0;
                #pragma unroll
                for (int j = 0; j < 16; ++j) fa[j] = fmaf(a, wr[j], fa[j]);
            }
            #pragma unroll
            for (int j = 0; j < 16; ++j) lds[Bb + (c0 + j) * 64 + lane] = fmaxf(fa[j], 0.f);
        }
        __syncthreads();
        {   // xr += F-hi @ W2[64:128]
            float acc[16];
            #pragma unroll
            for (int j = 0; j < 16; ++j) acc[j] = 0.f;
            #pragma unroll 8
            for (int kk = 0; kk < 64; ++kk) {
                float a = lds[Bb + kk * 64 + lane];
                const float* wr = fw2 + (64 + kk) * 64 + c0;
                #pragma unroll
                for (int j = 0; j < 16; ++j) acc[j] = fmaf(a, wr[j], acc[j]);
            }
            #pragma unroll
            for (int j = 0; j < 16; ++j) xr[j] += acc[j];
        }
        // next phase's LN barriers protect A/Bb reuse
    }

    // ================= reduction / calculator head =================
    LN_STORE(enc_g, enc_b, lds[Bb + lane * 65 + c_] = hv_);   // hR stride 65
    if (tid < 64) {       // scores = h @ red_w + red_b + (1-mask)*-1e9
        float s = 0.f;
        #pragma unroll 8
        for (int c2 = 0; c2 < 64; ++c2)
            s = fmaf(lds[Bb + tid * 65 + c2], red_w[c2], s);
        s += red_b[0];
        s += (1.f - lds[M_MASK + tid]) * -1e9f;
        lds[M_SU + tid] = s;
    }
    __syncthreads();

    if (wv == 0) {        // softmax, scans, digit assembly (wave 0)
        float s = lds[M_SU + lane];
        float m = s;
        #pragma unroll
        for (int off = 1; off < 64; off <<= 1) m = fmaxf(m, __shfl_xor(m, off));
        float ee = expf(s - m);
        float z = ee;
        #pragma unroll
        for (int off = 1; off < 64; off <<= 1) z += __shfl_xor(z, off);
        float rw = ee / z;
        lds[M_SD + lane] = rw;
        float cum = rw;
        #pragma unroll
        for (int off = 1; off < 64; off <<= 1) { float t2 = __shfl_up(cum, off); if (lane >= off) cum += t2; }
        float isd = lds[M_ISD + lane], dvv = lds[M_DVAL + lane];
        float lm = (1.f - cum) * isd;
        float rm = (cum - rw) * isd;
        float cl = lm;
        #pragma unroll
        for (int off = 1; off < 64; off <<= 1) { float t2 = __shfl_up(cl, off); if (lane >= off) cl += t2; }
        float totl = __shfl(cl, 63);
        float wL = powf(10.f, (totl - cl) * lm) * lm;
        float lv = dvv * wL;
        #pragma unroll
        for (int off = 1; off < 64; off <<= 1) lv += __shfl_xor(lv, off);
        float cr = rm;
        #pragma unroll
        for (int off = 1; off < 64; off <<= 1) { float t2 = __shfl_up(cr, off); if (lane >= off) cr += t2; }
        float totr = __shfl(cr, 63);
        float wR = powf(10.f, (totr - cr) * rm) * rm;
        float rv = dvv * wR;
        #pragma unroll
        for (int off = 1; off < 64; off <<= 1) rv += __shfl_xor(rv, off);
        if (lane == 0) { lds[M_DG + 2] = lv; lds[M_DG + 3] = rv; }
    }
    __syncthreads();

    if (tid < 64) {       // pooled[c] = sum_r h[r][c] * rw[r]
        float p = 0.f;
        #pragma unroll 8
        for (int r2 = 0; r2 < 64; ++r2)
            p = fmaf(lds[Bb + r2 * 65 + tid], lds[M_SD + r2], p);
        lds[M_NBU + tid] = p;
    }
    __syncthreads();
    if (tid < 4) {        // op logits
        float s = opc_b[tid];
        for (int c2 = 0; c2 < 64; ++c2) s = fmaf(lds[M_NBU + c2], opc_w[(c2 << 2) + tid], s);
        lds[M_DG + 4 + tid] = s;
    }
    __syncthreads();
    if (tid == 0) {       // hard argmax op select + fixed ops
        float l = lds[M_DG + 2], r = lds[M_DG + 3];
        float o0 = lds[M_DG + 4], o1 = lds[M_DG + 5], o2 = lds[M_DG + 6], o3 = lds[M_DG + 7];
        int op = 0; float bm = o0;
        if (o1 > bm) { bm = o1; op = 1; }
        if (o2 > bm) { bm = o2; op = 2; }
        if (o3 > bm) { bm = o3; op = 3; }
        float res, vl = 1.f;
        if (op == 0)      res = l + r;
        else if (op == 1) res = l - r;
        else if (op == 2) res = l * r;
        else { bool bad = fabsf(r) < 1e-6f; res = bad ? 0.f : (l / r); vl = bad ? 0.f : 1.f; }
        float rc = (res > 0.f) ? log1pf(res) : ((res < 0.f) ? -log1pf(-res) : 0.f);
        lds[M_DG + 0] = rc; lds[M_DG + 1] = vl;
        out[O_RES + b]   = res;
        out[O_VALID + b] = vl;
        out[O_LEFT + b]  = l;
        out[O_RIGHT + b] = r;
    }
    __syncthreads();
    if (tid < 64) {
        float rc = lds[M_DG + 0], vl = lds[M_DG + 1];
        out[O_REMB + (b << 6) + tid] = rc * res_w[tid] + vl * res_w[64 + tid] + res_b[tid];
        out[O_RW + (b << 6) + tid] = lds[M_SD + tid];
    }
    if (tid >= 64 && tid < 68) {
        int o = tid - 64;
        out[O_OPL + (b << 2) + o] = lds[M_DG + 4 + o];
    }
}

extern "C" void kernel_launch(void* const* d_in, const int* in_sizes, int n_in,
                              void* d_out, int out_size, void* d_ws, size_t ws_size,
                              hipStream_t stream)
{
    fsa_kernel<<<dim3(BATCH), dim3(256), 0, stream>>>(
        (const int*)d_in[0],
        (const float*)d_in[1],  (const float*)d_in[2],  (const float*)d_in[3],
        (const float*)d_in[4],  (const float*)d_in[5],  (const float*)d_in[6],  (const float*)d_in[7],
        (const float*)d_in[8],  (const float*)d_in[9],  (const float*)d_in[10], (const float*)d_in[11],
        (const float*)d_in[12], (const float*)d_in[13], (const float*)d_in[14], (const float*)d_in[15],
        (const float*)d_in[16], (const float*)d_in[17], (const float*)d_in[18], (const float*)d_in[19],
        (const float*)d_in[20], (const float*)d_in[21], (const float*)d_in[22], (const float*)d_in[23],
        (const float*)d_in[24], (const float*)d_in[25], (const float*)d_in[26], (const float*)d_in[27],
        (float*)d_out);
}